// Round 1
// baseline (4209.613 us; speedup 1.0000x reference)
//
#include <hip/hip_runtime.h>
#include <math.h>

#define B_ 16
#define L_ 720
#define C_ 128
#define H_ 96
#define F2_ 49
#define K_ 8
#define S_ 8
#define OUT_ 833          // F2*(2K+1)
#define SEQLEN 816        // L + H
#define C2T 16

// ---------------------------------------------------------------- K1: normalize
__global__ __launch_bounds__(256) void k1_norm(const float* __restrict__ x,
                                               const float* __restrict__ yh,
                                               float* __restrict__ seq,
                                               float* __restrict__ mu_g,
                                               float* __restrict__ std_g) {
  const int bc = blockIdx.x;            // b*C + c
  const int b = bc >> 7, c = bc & 127;
  const int tid = threadIdx.x;
  __shared__ float redA[4], redB[4];
  const float* xb = x + (size_t)b * L_ * C_ + c;   // element l at xb[l*C_]

  float s = 0.f;
  for (int l = tid; l < L_; l += 256) s += xb[(size_t)l * C_];
  for (int off = 32; off; off >>= 1) s += __shfl_down(s, off, 64);
  if ((tid & 63) == 0) redA[tid >> 6] = s;
  __syncthreads();
  const float mu = (redA[0] + redA[1] + redA[2] + redA[3]) * (1.0f / L_);

  float vs = 0.f;
  for (int l = tid; l < L_; l += 256) { float d = xb[(size_t)l * C_] - mu; vs += d * d; }
  for (int off = 32; off; off >>= 1) vs += __shfl_down(vs, off, 64);
  if ((tid & 63) == 0) redB[tid >> 6] = vs;
  __syncthreads();
  const float stdv = sqrtf((redB[0] + redB[1] + redB[2] + redB[3]) * (1.0f / L_) + 1e-8f);
  const float inv = 1.0f / stdv;

  float* sq = seq + (size_t)bc * SEQLEN;
  for (int l = tid; l < L_; l += 256) sq[l] = (xb[(size_t)l * C_] - mu) * inv;
  const float* yb = yh + (size_t)b * H_ * C_ + c;
  for (int h = tid; h < H_; h += 256) sq[L_ + h] = (yb[(size_t)h * C_] - mu) * inv;
  if (tid == 0) { mu_g[bc] = mu; std_g[bc] = stdv; }
}

// ---------------------------------------------------------------- K2: all-pair circular correlation + peak pick
__global__ __launch_bounds__(256) void k2_corr(const float* __restrict__ seq,
                                               float* __restrict__ r_arr,
                                               int* __restrict__ t_arr) {
  const int bid = blockIdx.x;           // grid = B * C * (C/C2T) = 16*128*8
  const int c2t = bid & 7;
  const int c1 = (bid >> 3) & 127;
  const int b = bid >> 10;
  const int tid = threadIdx.x;

  __shared__ __align__(16) float x1d[1504];          // x1 duplicated (mod-free) + zero pad
  __shared__ __align__(16) float xs[C2T][720];       // c2 rows; reused as cc storage after compute

  const float* seqb = seq + (size_t)b * C_ * SEQLEN;
  for (int i = tid; i < 720; i += 256) {
    float v = seqb[(size_t)c1 * SEQLEN + i];
    x1d[i] = v; x1d[i + 720] = v;
  }
  if (tid < 64) x1d[1440 + tid] = 0.f;
  const int c2base = c2t * C2T;
  for (int ci = 0; ci < C2T; ++ci)
    for (int i = tid; i < 720; i += 256)
      xs[ci][i] = seqb[(size_t)(c2base + ci) * SEQLEN + i];
  __syncthreads();

  float acc0[C2T], acc1[C2T], acc2[C2T];
#pragma unroll
  for (int ci = 0; ci < C2T; ++ci) { acc0[ci] = 0.f; acc1[ci] = 0.f; acc2[ci] = 0.f; }
  const int t0 = tid, t1 = tid + 256, t2 = tid + 512;  // t2 valid only if < 720

  for (int l = 0; l < 720; l += 4) {
    const float a00 = x1d[l + t0], a01 = x1d[l + t0 + 1], a02 = x1d[l + t0 + 2], a03 = x1d[l + t0 + 3];
    const float a10 = x1d[l + t1], a11 = x1d[l + t1 + 1], a12 = x1d[l + t1 + 2], a13 = x1d[l + t1 + 3];
    const float a20 = x1d[l + t2], a21 = x1d[l + t2 + 1], a22 = x1d[l + t2 + 2], a23 = x1d[l + t2 + 3];
#pragma unroll
    for (int ci = 0; ci < C2T; ++ci) {
      const float4 xv = *(const float4*)&xs[ci][l];
      float u0 = fmaf(a00, xv.x, acc0[ci]); u0 = fmaf(a01, xv.y, u0); u0 = fmaf(a02, xv.z, u0); u0 = fmaf(a03, xv.w, u0); acc0[ci] = u0;
      float u1 = fmaf(a10, xv.x, acc1[ci]); u1 = fmaf(a11, xv.y, u1); u1 = fmaf(a12, xv.z, u1); u1 = fmaf(a13, xv.w, u1); acc1[ci] = u1;
      float u2 = fmaf(a20, xv.x, acc2[ci]); u2 = fmaf(a21, xv.y, u2); u2 = fmaf(a22, xv.z, u2); u2 = fmaf(a23, xv.w, u2); acc2[ci] = u2;
    }
  }
  __syncthreads();                       // all xs reads done; safe to overwrite

  float (*ccs)[720] = xs;
#pragma unroll
  for (int ci = 0; ci < C2T; ++ci) {
    ccs[ci][t0] = acc0[ci];
    ccs[ci][t1] = acc1[ci];
    if (t2 < 720) ccs[ci][t2] = acc2[ci];
  }
  __syncthreads();

  // peak scan: 16 lanes per c2. Replicates: mask = local max of |cc| on t in [1,718];
  // masked non-peaks are value-0 candidates; argmax ties -> smallest t.
  const int g = tid >> 4;                // c2 index in tile
  const int lane = tid & 15;
  float bv = 0.f; int bt = 1;            // all-zero case => j=0 => t*=1, r=0
  for (int i = lane; i < 718; i += 16) {
    const int t = i + 1;
    const float v = fabsf(ccs[g][t]);
    const bool q = (v >= fabsf(ccs[g][t - 1])) && (v >= fabsf(ccs[g][t + 1]));
    const float cand = q ? v : 0.f;
    if (cand > bv || (cand == bv && t < bt)) { bv = cand; bt = t; }
  }
  for (int off = 8; off; off >>= 1) {
    const float ov = __shfl_down(bv, off, 16);
    const int ot = __shfl_down(bt, off, 16);
    if (ov > bv || (ov == bv && ot < bt)) { bv = ov; bt = ot; }
  }
  if (lane == 0) {
    const float r = (bv > 0.f) ? ccs[g][bt] * (1.0f / 720.0f) : 0.f;
    const size_t o = ((size_t)(b * C_ + c1)) * C_ + (c2base + g);
    r_arr[o] = r; t_arr[o] = bt;
  }
}

// ---------------------------------------------------------------- K3: top-k leaders, softmaxes, filt
__global__ __launch_bounds__(256) void k3_leaders(const float* __restrict__ x,
                                                  const float* __restrict__ temperature,
                                                  const float* __restrict__ cls_w,
                                                  const float* __restrict__ basic_state,
                                                  const float* __restrict__ state_bias,
                                                  const float* __restrict__ mhw,
                                                  const float* __restrict__ mhb,
                                                  const float* __restrict__ r_arr,
                                                  const int* __restrict__ t_arr,
                                                  int* __restrict__ lead_id,
                                                  int* __restrict__ lead_t,
                                                  float* __restrict__ lead_sr,
                                                  float* __restrict__ filt) {
  const int bc = blockIdx.x;
  const int b = bc >> 7, c = bc & 127;
  const int tid = threadIdx.x;
  __shared__ float caL[C_], rL[C_];
  __shared__ int tL[C_];
  __shared__ float cfL[K_], srL[K_], pL[S_], qL[S_ * K_], praw[S_];
  __shared__ int leadL[K_], ltL[K_];

  if (tid < C_) {
    const float r = r_arr[(size_t)bc * C_ + tid];
    rL[tid] = r; caL[tid] = fabsf(r);
    tL[tid] = t_arr[(size_t)bc * C_ + tid];
  }
  __syncthreads();

  if (tid == 0) {
    const float T = temperature[0];
    float lg[K_ + 1];
    lg[0] = 1.0f / T;
    for (int k = 0; k < K_; ++k) {       // stable top-k: strict > keeps smallest index on ties
      float bvv = -1.f; int bi = 0;
      for (int j = 0; j < C_; ++j) { const float v = caL[j]; if (v > bvv) { bvv = v; bi = j; } }
      leadL[k] = bi; ltL[k] = tL[bi];
      const float rv = rL[bi];
      srL[k] = (rv > 0.f) ? 1.f : ((rv < 0.f) ? -1.f : 0.f);
      lg[k + 1] = bvv / T;
      caL[bi] = -2.f;
    }
    float m = lg[0];
    for (int k = 1; k <= K_; ++k) m = fmaxf(m, lg[k]);
    float sum = 0.f, e[K_ + 1];
    for (int k = 0; k <= K_; ++k) { e[k] = expf(lg[k] - m); sum += e[k]; }
    const float invs = 1.0f / sum;
    for (int k = 0; k < K_; ++k) cfL[k] = e[k + 1] * invs;
  }
  __syncthreads();

  // p logits: 8 groups of 32 lanes, one state each
  {
    const int g = tid >> 5, lane = tid & 31;
    float acc = 0.f;
    const float* xb = x + (size_t)b * L_ * C_ + c;
    const float* w = cls_w + (size_t)g * L_;
    for (int l = lane; l < L_; l += 32) acc += xb[(size_t)l * C_] * w[l];
    for (int off = 16; off; off >>= 1) acc += __shfl_down(acc, off, 32);
    if (lane == 0) praw[g] = acc + state_bias[g] + basic_state[c * S_ + g];
  }
  __syncthreads();
  if (tid == 0) {
    float m = praw[0];
    for (int s2 = 1; s2 < S_; ++s2) m = fmaxf(m, praw[s2]);
    float sum = 0.f;
    for (int s2 = 0; s2 < S_; ++s2) { const float e = expf(praw[s2] - m); pL[s2] = e; sum += e; }
    const float invs = 1.0f / sum;
    for (int s2 = 0; s2 < S_; ++s2) pL[s2] *= invs;
    for (int s2 = 0; s2 < S_; ++s2)
      for (int k = 0; k < K_; ++k) qL[s2 * K_ + k] = pL[s2] * cfL[k];
  }
  __syncthreads();

  for (int o = tid; o < OUT_; o += 256) {
    float acc = 0.f;
#pragma unroll
    for (int s2 = 0; s2 < S_; ++s2) {
      acc += pL[s2] * mhb[s2 * OUT_ + o];
#pragma unroll
      for (int k = 0; k < K_; ++k)
        acc += qL[s2 * K_ + k] * mhw[(size_t)s2 * (K_ * OUT_) + k * OUT_ + o];
    }
    filt[(size_t)bc * OUT_ + o] = acc;
  }
  if (tid < K_) {
    lead_id[bc * K_ + tid] = leadL[tid];
    lead_t[bc * K_ + tid] = ltL[tid];
    lead_sr[bc * K_ + tid] = srL[tid];
  }
}

// ---------------------------------------------------------------- K4: spectral mix + output
__global__ __launch_bounds__(256) void k4_final(const float* __restrict__ seq,
                                                const float* __restrict__ mu_g,
                                                const float* __restrict__ std_g,
                                                const int* __restrict__ lead_id,
                                                const int* __restrict__ lead_t,
                                                const float* __restrict__ lead_sr,
                                                const float* __restrict__ filt,
                                                const float* __restrict__ mwr,
                                                const float* __restrict__ mwi,
                                                const float* __restrict__ mbr,
                                                const float* __restrict__ mbi,
                                                float* __restrict__ out) {
  const int bc = blockIdx.x;
  const int b = bc >> 7, c = bc & 127;
  const int tid = threadIdx.x;
  __shared__ float cosT[96], sinT[96];
  __shared__ float ssL[K_][H_], ynL[H_], flL[OUT_];
  __shared__ float sfr[K_][F2_], sfi[K_][F2_], yfr[F2_], yfi[F2_];
  __shared__ float catr[3 * F2_], cati[3 * F2_], ofr[F2_], ofi[F2_];
  __shared__ int ldL[K_], ltL[K_];
  __shared__ float srL[K_];

  if (tid < 96) {
    const float ang = (float)tid * (float)(6.283185307179586 / 96.0);
    cosT[tid] = cosf(ang); sinT[tid] = sinf(ang);
    ynL[tid] = seq[(size_t)bc * SEQLEN + L_ + tid];
  }
  if (tid >= 96 && tid < 96 + K_) {
    const int k = tid - 96;
    ldL[k] = lead_id[bc * K_ + k];
    ltL[k] = lead_t[bc * K_ + k];
    srL[k] = lead_sr[bc * K_ + k];
  }
  for (int o = tid; o < OUT_; o += 256) flL[o] = filt[(size_t)bc * OUT_ + o];
  __syncthreads();

  for (int i = tid; i < K_ * H_; i += 256) {     // gather shifted leader windows
    const int k = i / H_, h = i - k * H_;
    ssL[k][h] = seq[((size_t)(b * C_ + ldL[k])) * SEQLEN + (L_ + h - ltL[k])] * srL[k];
  }
  __syncthreads();

  for (int u = tid; u < K_ * F2_ + F2_; u += 256) {    // 96-pt rfft (DFT) of ss rows and yn
    if (u < K_ * F2_) {
      const int k = u / F2_, f = u - k * F2_;
      float re = 0.f, im = 0.f; int m = 0;
      for (int h = 0; h < H_; ++h) {
        const float v = ssL[k][h];
        re = fmaf(v, cosT[m], re); im = fmaf(-v, sinT[m], im);
        m += f; if (m >= 96) m -= 96;
      }
      sfr[k][f] = re; sfi[k][f] = im;
    } else {
      const int f = u - K_ * F2_;
      float re = 0.f, im = 0.f; int m = 0;
      for (int h = 0; h < H_; ++h) {
        const float v = ynL[h];
        re = fmaf(v, cosT[m], re); im = fmaf(-v, sinT[m], im);
        m += f; if (m >= 96) m -= 96;
      }
      yfr[f] = re; yfi[f] = im;
    }
  }
  __syncthreads();

  if (tid < F2_) {
    const int f = tid;
    float s1r = 0.f, s1i = 0.f, s2r = 0.f, s2i = 0.f;
    const float yr = yfr[f], yi = yfi[f];
#pragma unroll
    for (int k = 0; k < K_; ++k) {
      const float fa = flL[k * F2_ + f], fb = flL[(K_ + k) * F2_ + f];
      const float ar = sfr[k][f] * fa, ai = sfi[k][f] * fa;
      s1r += ar; s1i += ai;
      s2r += (ar - yr) * fb; s2i += (ai - yi) * fb;
    }
    const float fc = flL[2 * K_ * F2_ + f];
    catr[f] = s1r;            cati[f] = s1i;
    catr[F2_ + f] = s2r;      cati[F2_ + f] = s2i;
    catr[2 * F2_ + f] = yr * fc; cati[2 * F2_ + f] = yi * fc;
  }
  __syncthreads();

  if (tid < F2_) {
    const int o = tid;
    float ar = mbr[o], ai = mbi[o];
    const float* wr = mwr + (size_t)o * (3 * F2_);
    const float* wi = mwi + (size_t)o * (3 * F2_);
    for (int f = 0; f < 3 * F2_; ++f) {
      const float cr = catr[f], ci = cati[f];
      const float wrr = wr[f], wii = wi[f];
      ar += cr * wrr - ci * wii;
      ai += cr * wii + ci * wrr;
    }
    ofr[o] = ar; ofi[o] = ai;
  }
  __syncthreads();

  if (tid < H_) {
    const int h = tid;
    float val = ofr[0] + ofr[48] * ((h & 1) ? -1.f : 1.f);
    int m = h;                                  // (f*h)%96 for f=1
    for (int f = 1; f < 48; ++f) {
      val += 2.f * (ofr[f] * cosT[m] - ofi[f] * sinT[m]);
      m += h; if (m >= 96) m -= 96;
    }
    val *= (1.0f / 96.0f);
    const float mu = mu_g[bc], stdv = std_g[bc];
    out[((size_t)b * H_ + h) * C_ + c] = (ynL[h] + val) * stdv + mu;
  }
}

// ---------------------------------------------------------------- launch
extern "C" void kernel_launch(void* const* d_in, const int* in_sizes, int n_in,
                              void* d_out, int out_size, void* d_ws, size_t ws_size,
                              hipStream_t stream) {
  const float* x    = (const float*)d_in[0];
  const float* yh   = (const float*)d_in[1];
  const float* temp = (const float*)d_in[2];
  const float* clsw = (const float*)d_in[3];
  const float* bst  = (const float*)d_in[4];
  const float* sbias= (const float*)d_in[5];
  const float* mhw  = (const float*)d_in[6];
  const float* mhb  = (const float*)d_in[7];
  const float* mwr  = (const float*)d_in[8];
  const float* mwi  = (const float*)d_in[9];
  const float* mbr  = (const float*)d_in[10];
  const float* mbi  = (const float*)d_in[11];
  float* out = (float*)d_out;

  float* ws = (float*)d_ws;
  float* seq    = ws;                                   // 2048*816
  float* mu_g   = seq + (size_t)2048 * SEQLEN;          // 2048
  float* std_g  = mu_g + 2048;                          // 2048
  float* r_arr  = std_g + 2048;                         // 262144
  float* filt   = r_arr + (size_t)2048 * C_;            // 2048*833
  int*   t_arr  = (int*)(filt + (size_t)2048 * OUT_);   // 262144
  int*   lead_i = t_arr + (size_t)2048 * C_;            // 16384
  int*   lead_t = lead_i + 2048 * K_;                   // 16384
  float* lead_s = (float*)(lead_t + 2048 * K_);         // 16384

  hipLaunchKernelGGL(k1_norm, dim3(B_ * C_), dim3(256), 0, stream, x, yh, seq, mu_g, std_g);
  hipLaunchKernelGGL(k2_corr, dim3(B_ * C_ * (C_ / C2T)), dim3(256), 0, stream, seq, r_arr, t_arr);
  hipLaunchKernelGGL(k3_leaders, dim3(B_ * C_), dim3(256), 0, stream,
                     x, temp, clsw, bst, sbias, mhw, mhb, r_arr, t_arr,
                     lead_i, lead_t, lead_s, filt);
  hipLaunchKernelGGL(k4_final, dim3(B_ * C_), dim3(256), 0, stream,
                     seq, mu_g, std_g, lead_i, lead_t, lead_s, filt,
                     mwr, mwi, mbr, mbi, out);
}

// Round 2
// 2758.568 us; speedup vs baseline: 1.5260x; 1.5260x over previous
//
#include <hip/hip_runtime.h>
#include <math.h>

#define B_ 16
#define L_ 720
#define C_ 128
#define H_ 96
#define F2_ 49
#define K_ 8
#define S_ 8
#define OUT_ 833          // F2*(2K+1)
#define SEQLEN 816        // L + H
#define C2T 16

// ---------------------------------------------------------------- K1: normalize
__global__ __launch_bounds__(256) void k1_norm(const float* __restrict__ x,
                                               const float* __restrict__ yh,
                                               float* __restrict__ seq,
                                               float* __restrict__ mu_g,
                                               float* __restrict__ std_g) {
  const int bc = blockIdx.x;            // b*C + c
  const int b = bc >> 7, c = bc & 127;
  const int tid = threadIdx.x;
  __shared__ float redA[4], redB[4];
  const float* xb = x + (size_t)b * L_ * C_ + c;   // element l at xb[l*C_]

  float s = 0.f;
  for (int l = tid; l < L_; l += 256) s += xb[(size_t)l * C_];
  for (int off = 32; off; off >>= 1) s += __shfl_down(s, off, 64);
  if ((tid & 63) == 0) redA[tid >> 6] = s;
  __syncthreads();
  const float mu = (redA[0] + redA[1] + redA[2] + redA[3]) * (1.0f / L_);

  float vs = 0.f;
  for (int l = tid; l < L_; l += 256) { float d = xb[(size_t)l * C_] - mu; vs += d * d; }
  for (int off = 32; off; off >>= 1) vs += __shfl_down(vs, off, 64);
  if ((tid & 63) == 0) redB[tid >> 6] = vs;
  __syncthreads();
  const float stdv = sqrtf((redB[0] + redB[1] + redB[2] + redB[3]) * (1.0f / L_) + 1e-8f);
  const float inv = 1.0f / stdv;

  float* sq = seq + (size_t)bc * SEQLEN;
  for (int l = tid; l < L_; l += 256) sq[l] = (xb[(size_t)l * C_] - mu) * inv;
  const float* yb = yh + (size_t)b * H_ * C_ + c;
  for (int h = tid; h < H_; h += 256) sq[L_ + h] = (yb[(size_t)h * C_] - mu) * inv;
  if (tid == 0) { mu_g[bc] = mu; std_g[bc] = stdv; }
}

// ---------------------------------------------------------------- K2: upper-triangle circular correlation + mirrored peak pick
// cc[c1][c2][t] = cc[c2][c1][(L-t)%L]  =>  compute tile pairs with c2tile >= tile(c1) only,
// emit forward results for c2 >= c1 and mirrored results for c2 > c1.
__global__ __launch_bounds__(256, 3) void k2_corr(const float* __restrict__ seq,
                                                  float* __restrict__ r_arr,
                                                  int* __restrict__ t_arr) {
  // grid = B * 576; 576 = sum over tile-group g of 16*(8-g)
  int idx = blockIdx.x;
  const int b = idx / 576;
  idx -= b * 576;
  int g = 0;
  while (true) { const int cnt = (8 - g) << 4; if (idx < cnt) break; idx -= cnt; ++g; }
  const int rows = 8 - g;
  const int c1 = (g << 4) + idx / rows;
  const int c2t = g + idx % rows;
  const int tid = threadIdx.x;

  __shared__ __align__(16) float x1d[1504];          // x1 duplicated (mod-free) + zero pad
  __shared__ __align__(16) float xs[C2T][720];       // c2 rows; reused as cc storage after compute

  const float* seqb = seq + (size_t)b * C_ * SEQLEN;
  for (int i = tid; i < 720; i += 256) {
    float v = seqb[(size_t)c1 * SEQLEN + i];
    x1d[i] = v; x1d[i + 720] = v;
  }
  if (tid < 64) x1d[1440 + tid] = 0.f;
  const int c2base = c2t * C2T;
  for (int ci = 0; ci < C2T; ++ci)
    for (int i = tid; i < 720; i += 256)
      xs[ci][i] = seqb[(size_t)(c2base + ci) * SEQLEN + i];
  __syncthreads();

  float acc0[C2T], acc1[C2T], acc2[C2T];
#pragma unroll
  for (int ci = 0; ci < C2T; ++ci) { acc0[ci] = 0.f; acc1[ci] = 0.f; acc2[ci] = 0.f; }
  const int t0 = tid, t1 = tid + 256, t2 = tid + 512;  // t2 valid only if < 720

  for (int l = 0; l < 720; l += 4) {
    const float a00 = x1d[l + t0], a01 = x1d[l + t0 + 1], a02 = x1d[l + t0 + 2], a03 = x1d[l + t0 + 3];
    const float a10 = x1d[l + t1], a11 = x1d[l + t1 + 1], a12 = x1d[l + t1 + 2], a13 = x1d[l + t1 + 3];
    const float a20 = x1d[l + t2], a21 = x1d[l + t2 + 1], a22 = x1d[l + t2 + 2], a23 = x1d[l + t2 + 3];
#pragma unroll
    for (int ci = 0; ci < C2T; ++ci) {
      const float4 xv = *(const float4*)&xs[ci][l];
      float u0 = fmaf(a00, xv.x, acc0[ci]); u0 = fmaf(a01, xv.y, u0); u0 = fmaf(a02, xv.z, u0); u0 = fmaf(a03, xv.w, u0); acc0[ci] = u0;
      float u1 = fmaf(a10, xv.x, acc1[ci]); u1 = fmaf(a11, xv.y, u1); u1 = fmaf(a12, xv.z, u1); u1 = fmaf(a13, xv.w, u1); acc1[ci] = u1;
      float u2 = fmaf(a20, xv.x, acc2[ci]); u2 = fmaf(a21, xv.y, u2); u2 = fmaf(a22, xv.z, u2); u2 = fmaf(a23, xv.w, u2); acc2[ci] = u2;
    }
  }
  __syncthreads();                       // all xs reads done; safe to overwrite

  float (*ccs)[720] = xs;
#pragma unroll
  for (int ci = 0; ci < C2T; ++ci) {
    ccs[ci][t0] = acc0[ci];
    ccs[ci][t1] = acc1[ci];
    if (t2 < 720) ccs[ci][t2] = acc2[ci];
  }
  __syncthreads();

  // peak scans: 16 lanes per c2 row. Replicates ref: mask = local max of |cc| on t in [1,718];
  // masked non-peaks are value-0 candidates; argmax ties -> smallest t.
  const int gq = tid >> 4;               // c2 index in tile
  const int lane = tid & 15;
  const int c2 = c2base + gq;
  const float* cr = ccs[gq];

  // ---- forward: pair (c1, c2)
  if (c2 >= c1) {
    float bv = 0.f; int bt = 1;
    for (int i = lane; i < 718; i += 16) {
      const int t = i + 1;
      const float v = fabsf(cr[t]);
      const bool q = (v >= fabsf(cr[t - 1])) && (v >= fabsf(cr[t + 1]));
      const float cand = q ? v : 0.f;
      if (cand > bv || (cand == bv && t < bt)) { bv = cand; bt = t; }
    }
    for (int off = 8; off; off >>= 1) {
      const float ov = __shfl_down(bv, off, 16);
      const int ot = __shfl_down(bt, off, 16);
      if (ov > bv || (ov == bv && ot < bt)) { bv = ov; bt = ot; }
    }
    if (lane == 0) {
      const float r = (bv > 0.f) ? cr[bt] * (1.0f / 720.0f) : 0.f;
      const size_t o = ((size_t)(b * C_ + c1)) * C_ + c2;
      r_arr[o] = r; t_arr[o] = bt;
    }
  }

  // ---- mirrored: pair (c2, c1), cc_m[t] = cc[(720 - t) % 720]
  if (c2 > c1) {
    float bv = 0.f; int bt = 1;
    for (int i = lane; i < 718; i += 16) {
      const int t = i + 1;
      const int u = 720 - t;                         // in [2, 719]
      const float v = fabsf(cr[u]);
      const float lft = fabsf(cr[(u == 719) ? 0 : (u + 1)]);   // cc_m[t-1]
      const float rgt = fabsf(cr[u - 1]);                      // cc_m[t+1]
      const bool q = (v >= lft) && (v >= rgt);
      const float cand = q ? v : 0.f;
      if (cand > bv || (cand == bv && t < bt)) { bv = cand; bt = t; }
    }
    for (int off = 8; off; off >>= 1) {
      const float ov = __shfl_down(bv, off, 16);
      const int ot = __shfl_down(bt, off, 16);
      if (ov > bv || (ov == bv && ot < bt)) { bv = ov; bt = ot; }
    }
    if (lane == 0) {
      const float r = (bv > 0.f) ? cr[720 - bt] * (1.0f / 720.0f) : 0.f;
      const size_t o = ((size_t)(b * C_ + c2)) * C_ + c1;
      r_arr[o] = r; t_arr[o] = bt;
    }
  }
}

// ---------------------------------------------------------------- K3: top-k leaders, softmaxes, filt
__global__ __launch_bounds__(256) void k3_leaders(const float* __restrict__ x,
                                                  const float* __restrict__ temperature,
                                                  const float* __restrict__ cls_w,
                                                  const float* __restrict__ basic_state,
                                                  const float* __restrict__ state_bias,
                                                  const float* __restrict__ mhw,
                                                  const float* __restrict__ mhb,
                                                  const float* __restrict__ r_arr,
                                                  const int* __restrict__ t_arr,
                                                  int* __restrict__ lead_id,
                                                  int* __restrict__ lead_t,
                                                  float* __restrict__ lead_sr,
                                                  float* __restrict__ filt) {
  const int bc = blockIdx.x;
  const int b = bc >> 7, c = bc & 127;
  const int tid = threadIdx.x;
  __shared__ float caL[C_], rL[C_];
  __shared__ int tL[C_];
  __shared__ float cfL[K_], srL[K_], pL[S_], qL[S_ * K_], praw[S_];
  __shared__ int leadL[K_], ltL[K_];

  if (tid < C_) {
    const float r = r_arr[(size_t)bc * C_ + tid];
    rL[tid] = r; caL[tid] = fabsf(r);
    tL[tid] = t_arr[(size_t)bc * C_ + tid];
  }
  __syncthreads();

  if (tid == 0) {
    const float T = temperature[0];
    float lg[K_ + 1];
    lg[0] = 1.0f / T;
    for (int k = 0; k < K_; ++k) {       // stable top-k: strict > keeps smallest index on ties
      float bvv = -1.f; int bi = 0;
      for (int j = 0; j < C_; ++j) { const float v = caL[j]; if (v > bvv) { bvv = v; bi = j; } }
      leadL[k] = bi; ltL[k] = tL[bi];
      const float rv = rL[bi];
      srL[k] = (rv > 0.f) ? 1.f : ((rv < 0.f) ? -1.f : 0.f);
      lg[k + 1] = bvv / T;
      caL[bi] = -2.f;
    }
    float m = lg[0];
    for (int k = 1; k <= K_; ++k) m = fmaxf(m, lg[k]);
    float sum = 0.f, e[K_ + 1];
    for (int k = 0; k <= K_; ++k) { e[k] = expf(lg[k] - m); sum += e[k]; }
    const float invs = 1.0f / sum;
    for (int k = 0; k < K_; ++k) cfL[k] = e[k + 1] * invs;
  }
  __syncthreads();

  // p logits: 8 groups of 32 lanes, one state each
  {
    const int g = tid >> 5, lane = tid & 31;
    float acc = 0.f;
    const float* xb = x + (size_t)b * L_ * C_ + c;
    const float* w = cls_w + (size_t)g * L_;
    for (int l = lane; l < L_; l += 32) acc += xb[(size_t)l * C_] * w[l];
    for (int off = 16; off; off >>= 1) acc += __shfl_down(acc, off, 32);
    if (lane == 0) praw[g] = acc + state_bias[g] + basic_state[c * S_ + g];
  }
  __syncthreads();
  if (tid == 0) {
    float m = praw[0];
    for (int s2 = 1; s2 < S_; ++s2) m = fmaxf(m, praw[s2]);
    float sum = 0.f;
    for (int s2 = 0; s2 < S_; ++s2) { const float e = expf(praw[s2] - m); pL[s2] = e; sum += e; }
    const float invs = 1.0f / sum;
    for (int s2 = 0; s2 < S_; ++s2) pL[s2] *= invs;
    for (int s2 = 0; s2 < S_; ++s2)
      for (int k = 0; k < K_; ++k) qL[s2 * K_ + k] = pL[s2] * cfL[k];
  }
  __syncthreads();

  for (int o = tid; o < OUT_; o += 256) {
    float acc = 0.f;
#pragma unroll
    for (int s2 = 0; s2 < S_; ++s2) {
      acc += pL[s2] * mhb[s2 * OUT_ + o];
#pragma unroll
      for (int k = 0; k < K_; ++k)
        acc += qL[s2 * K_ + k] * mhw[(size_t)s2 * (K_ * OUT_) + k * OUT_ + o];
    }
    filt[(size_t)bc * OUT_ + o] = acc;
  }
  if (tid < K_) {
    lead_id[bc * K_ + tid] = leadL[tid];
    lead_t[bc * K_ + tid] = ltL[tid];
    lead_sr[bc * K_ + tid] = srL[tid];
  }
}

// ---------------------------------------------------------------- K4: spectral mix + output
__global__ __launch_bounds__(256) void k4_final(const float* __restrict__ seq,
                                                const float* __restrict__ mu_g,
                                                const float* __restrict__ std_g,
                                                const int* __restrict__ lead_id,
                                                const int* __restrict__ lead_t,
                                                const float* __restrict__ lead_sr,
                                                const float* __restrict__ filt,
                                                const float* __restrict__ mwr,
                                                const float* __restrict__ mwi,
                                                const float* __restrict__ mbr,
                                                const float* __restrict__ mbi,
                                                float* __restrict__ out) {
  const int bc = blockIdx.x;
  const int b = bc >> 7, c = bc & 127;
  const int tid = threadIdx.x;
  __shared__ float cosT[96], sinT[96];
  __shared__ float ssL[K_][H_], ynL[H_], flL[OUT_];
  __shared__ float sfr[K_][F2_], sfi[K_][F2_], yfr[F2_], yfi[F2_];
  __shared__ float catr[3 * F2_], cati[3 * F2_], ofr[F2_], ofi[F2_];
  __shared__ int ldL[K_], ltL[K_];
  __shared__ float srL[K_];

  if (tid < 96) {
    const float ang = (float)tid * (float)(6.283185307179586 / 96.0);
    cosT[tid] = cosf(ang); sinT[tid] = sinf(ang);
    ynL[tid] = seq[(size_t)bc * SEQLEN + L_ + tid];
  }
  if (tid >= 96 && tid < 96 + K_) {
    const int k = tid - 96;
    ldL[k] = lead_id[bc * K_ + k];
    ltL[k] = lead_t[bc * K_ + k];
    srL[k] = lead_sr[bc * K_ + k];
  }
  for (int o = tid; o < OUT_; o += 256) flL[o] = filt[(size_t)bc * OUT_ + o];
  __syncthreads();

  for (int i = tid; i < K_ * H_; i += 256) {     // gather shifted leader windows
    const int k = i / H_, h = i - k * H_;
    ssL[k][h] = seq[((size_t)(b * C_ + ldL[k])) * SEQLEN + (L_ + h - ltL[k])] * srL[k];
  }
  __syncthreads();

  for (int u = tid; u < K_ * F2_ + F2_; u += 256) {    // 96-pt rfft (DFT) of ss rows and yn
    if (u < K_ * F2_) {
      const int k = u / F2_, f = u - k * F2_;
      float re = 0.f, im = 0.f; int m = 0;
      for (int h = 0; h < H_; ++h) {
        const float v = ssL[k][h];
        re = fmaf(v, cosT[m], re); im = fmaf(-v, sinT[m], im);
        m += f; if (m >= 96) m -= 96;
      }
      sfr[k][f] = re; sfi[k][f] = im;
    } else {
      const int f = u - K_ * F2_;
      float re = 0.f, im = 0.f; int m = 0;
      for (int h = 0; h < H_; ++h) {
        const float v = ynL[h];
        re = fmaf(v, cosT[m], re); im = fmaf(-v, sinT[m], im);
        m += f; if (m >= 96) m -= 96;
      }
      yfr[f] = re; yfi[f] = im;
    }
  }
  __syncthreads();

  if (tid < F2_) {
    const int f = tid;
    float s1r = 0.f, s1i = 0.f, s2r = 0.f, s2i = 0.f;
    const float yr = yfr[f], yi = yfi[f];
#pragma unroll
    for (int k = 0; k < K_; ++k) {
      const float fa = flL[k * F2_ + f], fb = flL[(K_ + k) * F2_ + f];
      const float ar = sfr[k][f] * fa, ai = sfi[k][f] * fa;
      s1r += ar; s1i += ai;
      s2r += (ar - yr) * fb; s2i += (ai - yi) * fb;
    }
    const float fc = flL[2 * K_ * F2_ + f];
    catr[f] = s1r;            cati[f] = s1i;
    catr[F2_ + f] = s2r;      cati[F2_ + f] = s2i;
    catr[2 * F2_ + f] = yr * fc; cati[2 * F2_ + f] = yi * fc;
  }
  __syncthreads();

  if (tid < F2_) {
    const int o = tid;
    float ar = mbr[o], ai = mbi[o];
    const float* wr = mwr + (size_t)o * (3 * F2_);
    const float* wi = mwi + (size_t)o * (3 * F2_);
    for (int f = 0; f < 3 * F2_; ++f) {
      const float cr = catr[f], ci = cati[f];
      const float wrr = wr[f], wii = wi[f];
      ar += cr * wrr - ci * wii;
      ai += cr * wii + ci * wrr;
    }
    ofr[o] = ar; ofi[o] = ai;
  }
  __syncthreads();

  if (tid < H_) {
    const int h = tid;
    float val = ofr[0] + ofr[48] * ((h & 1) ? -1.f : 1.f);
    int m = h;                                  // (f*h)%96 for f=1
    for (int f = 1; f < 48; ++f) {
      val += 2.f * (ofr[f] * cosT[m] - ofi[f] * sinT[m]);
      m += h; if (m >= 96) m -= 96;
    }
    val *= (1.0f / 96.0f);
    const float mu = mu_g[bc], stdv = std_g[bc];
    out[((size_t)b * H_ + h) * C_ + c] = (ynL[h] + val) * stdv + mu;
  }
}

// ---------------------------------------------------------------- launch
extern "C" void kernel_launch(void* const* d_in, const int* in_sizes, int n_in,
                              void* d_out, int out_size, void* d_ws, size_t ws_size,
                              hipStream_t stream) {
  const float* x    = (const float*)d_in[0];
  const float* yh   = (const float*)d_in[1];
  const float* temp = (const float*)d_in[2];
  const float* clsw = (const float*)d_in[3];
  const float* bst  = (const float*)d_in[4];
  const float* sbias= (const float*)d_in[5];
  const float* mhw  = (const float*)d_in[6];
  const float* mhb  = (const float*)d_in[7];
  const float* mwr  = (const float*)d_in[8];
  const float* mwi  = (const float*)d_in[9];
  const float* mbr  = (const float*)d_in[10];
  const float* mbi  = (const float*)d_in[11];
  float* out = (float*)d_out;

  float* ws = (float*)d_ws;
  float* seq    = ws;                                   // 2048*816
  float* mu_g   = seq + (size_t)2048 * SEQLEN;          // 2048
  float* std_g  = mu_g + 2048;                          // 2048
  float* r_arr  = std_g + 2048;                         // 262144
  float* filt   = r_arr + (size_t)2048 * C_;            // 2048*833
  int*   t_arr  = (int*)(filt + (size_t)2048 * OUT_);   // 262144
  int*   lead_i = t_arr + (size_t)2048 * C_;            // 16384
  int*   lead_t = lead_i + 2048 * K_;                   // 16384
  float* lead_s = (float*)(lead_t + 2048 * K_);         // 16384

  hipLaunchKernelGGL(k1_norm, dim3(B_ * C_), dim3(256), 0, stream, x, yh, seq, mu_g, std_g);
  hipLaunchKernelGGL(k2_corr, dim3(B_ * 576), dim3(256), 0, stream, seq, r_arr, t_arr);
  hipLaunchKernelGGL(k3_leaders, dim3(B_ * C_), dim3(256), 0, stream,
                     x, temp, clsw, bst, sbias, mhw, mhb, r_arr, t_arr,
                     lead_i, lead_t, lead_s, filt);
  hipLaunchKernelGGL(k4_final, dim3(B_ * C_), dim3(256), 0, stream,
                     seq, mu_g, std_g, lead_i, lead_t, lead_s, filt,
                     mwr, mwi, mbr, mbi, out);
}

// Round 3
// 1906.756 us; speedup vs baseline: 2.2077x; 1.4467x over previous
//
#include <hip/hip_runtime.h>
#include <math.h>

#define B_ 16
#define L_ 720
#define C_ 128
#define H_ 96
#define F2_ 49
#define K_ 8
#define S_ 8
#define OUT_ 833          // F2*(2K+1)
#define SEQLEN 816        // L + H
#define NF 361            // rfft bins for L=720
#define PADP 724          // padded row (float2) for P buffer
#define CCSTRIDE (2*PADP) // cc row stride in floats (overlaying P)

__device__ __forceinline__ float2 cmulp(float2 a, float2 w) {   // a * w (complex)
  return make_float2(a.x*w.x - a.y*w.y, a.x*w.y + a.y*w.x);
}

// ---------------------------------------------------------------- K1: normalize
__global__ __launch_bounds__(256) void k1_norm(const float* __restrict__ x,
                                               const float* __restrict__ yh,
                                               float* __restrict__ seq,
                                               float* __restrict__ mu_g,
                                               float* __restrict__ std_g) {
  const int bc = blockIdx.x;            // b*C + c
  const int b = bc >> 7, c = bc & 127;
  const int tid = threadIdx.x;
  __shared__ float redA[4], redB[4];
  const float* xb = x + (size_t)b * L_ * C_ + c;   // element l at xb[l*C_]

  float s = 0.f;
  for (int l = tid; l < L_; l += 256) s += xb[(size_t)l * C_];
  for (int off = 32; off; off >>= 1) s += __shfl_down(s, off, 64);
  if ((tid & 63) == 0) redA[tid >> 6] = s;
  __syncthreads();
  const float mu = (redA[0] + redA[1] + redA[2] + redA[3]) * (1.0f / L_);

  float vs = 0.f;
  for (int l = tid; l < L_; l += 256) { float d = xb[(size_t)l * C_] - mu; vs += d * d; }
  for (int off = 32; off; off >>= 1) vs += __shfl_down(vs, off, 64);
  if ((tid & 63) == 0) redB[tid >> 6] = vs;
  __syncthreads();
  const float stdv = sqrtf((redB[0] + redB[1] + redB[2] + redB[3]) * (1.0f / L_) + 1e-8f);
  const float inv = 1.0f / stdv;

  float* sq = seq + (size_t)bc * SEQLEN;
  for (int l = tid; l < L_; l += 256) sq[l] = (xb[(size_t)l * C_] - mu) * inv;
  const float* yb = yh + (size_t)b * H_ * C_ + c;
  for (int h = tid; h < H_; h += 256) sq[L_ + h] = (yb[(size_t)h * C_] - mu) * inv;
  if (tid == 0) { mu_g[bc] = mu; std_g[bc] = stdv; }
}

// ---------------------------------------------------------------- K1f: forward rfft (naive DFT, negative exponent)
__global__ __launch_bounds__(256) void k1f_fwd(const float* __restrict__ seq,
                                               float2* __restrict__ Rc) {
  const int bc = blockIdx.x;
  const int tid = threadIdx.x;
  __shared__ float xrow[L_];
  __shared__ float ct[L_], st[L_];
  for (int k = tid; k < L_; k += 256) {
    double ang = (double)k * 0.008726646259971647884;   // 2*pi/720
    ct[k] = (float)cos(ang); st[k] = (float)sin(ang);
    xrow[k] = seq[(size_t)bc * SEQLEN + k];
  }
  __syncthreads();
  for (int f = tid; f < NF; f += 256) {
    float re = 0.f, im = 0.f;
    int m = 0;
    for (int l = 0; l < L_; ++l) {
      const float v = xrow[l];
      re = fmaf(v, ct[m], re);
      im = fmaf(-v, st[m], im);
      m += f; if (m >= L_) m -= L_;
    }
    Rc[(size_t)bc * NF + f] = make_float2(re, im);
  }
}

// ---------------------------------------------------------------- K2: spectral pairwise product + 720-pt IFFT (16x45 CT) + peak pick
// cc[c1][c2][t] = cc[c2][c1][(L-t)%L] => triangle of 16-wide c2 tiles; emit fwd (c2>=c1) and mirror (c2>c1).
__global__ __launch_bounds__(256, 2) void k2_fft(const float2* __restrict__ Rc,
                                                 float* __restrict__ r_arr,
                                                 int* __restrict__ t_arr) {
  // grid = B * 576; 576 = sum over tile-group g of 16*(8-g)
  int idx = blockIdx.x;
  const int b = idx / 576;
  idx -= b * 576;
  int g = 0;
  while (true) { const int cnt = (8 - g) << 4; if (idx < cnt) break; idx -= cnt; ++g; }
  const int rows = 8 - g;
  const int c1 = (g << 4) + idx / rows;
  const int c2t = g + idx % rows;
  const int c2base = c2t << 4;
  const int tid = threadIdx.x;

  __shared__ float2 wtab[720];       // e^{+2*pi*i*k/720}
  __shared__ float2 t9[81];          // W9^{a*c} at [9a+c]
  __shared__ float2 t45[45];         // W45^{b*c} at [9b+c]
  __shared__ float2 r1c[NF];
  __shared__ float2 Pc[4 * PADP];    // Hermitian spectra of 4 pairs; later overlaid by cc rows
  __shared__ float2 Yc[4 * 720];     // stage-1 output

  for (int k = tid; k < 720; k += 256) {
    double ang = (double)k * 0.008726646259971647884;
    wtab[k] = make_float2((float)cos(ang), (float)sin(ang));
  }
  for (int f = tid; f < NF; f += 256)
    r1c[f] = Rc[((size_t)(b * C_ + c1)) * NF + f];
  __syncthreads();
  for (int i = tid; i < 81; i += 256) { int a = i / 9, c = i % 9; t9[i] = wtab[80 * ((a * c) % 9)]; }
  for (int i = tid; i < 45; i += 256) { int bb = i / 9, c = i % 9; t45[i] = wtab[16 * bb * c]; }
  __syncthreads();

  const float2* R2base = Rc + ((size_t)(b * C_ + c2base)) * NF;
  const float SCALE = 1.0f / 518400.0f;   // 1/720^2 (unnormalized IFFT -> r)

  for (int ch = 0; ch < 4; ++ch) {
    // ---- P build: Pfull = Hermitian-extended R1 * conj(R2), 4 pairs
    for (int u = tid; u < 4 * 720; u += 256) {
      const int j = u / 720, fp = u - j * 720;
      const int f = (fp <= 360) ? fp : 720 - fp;
      const float2 a = r1c[f];
      const float2 v = R2base[(size_t)(4 * ch + j) * NF + f];
      const float pr = a.x * v.x + a.y * v.y;
      float pi = a.y * v.x - a.x * v.y;
      if (fp > 360) pi = -pi;
      Pc[j * PADP + fp] = make_float2(pr, pi);
    }
    __syncthreads();

    // ---- stage 1: 45 DFT-16 (over n1) + twiddle, per pair. n = 45*n1 + n2, k = k1 + 16*k2.
    if (tid < 180) {
      const int j = tid / 45, n2 = tid - j * 45;
      float2 z[16];
#pragma unroll
      for (int n1 = 0; n1 < 16; ++n1) z[n1] = Pc[j * PADP + 45 * n1 + n2];
      float2 u4[4][4];
#pragma unroll
      for (int bb = 0; bb < 4; ++bb) {
        const float2 p0 = z[bb], p1 = z[4 + bb], p2 = z[8 + bb], p3 = z[12 + bb];
        const float t0r = p0.x + p2.x, t0i = p0.y + p2.y;
        const float t1r = p0.x - p2.x, t1i = p0.y - p2.y;
        const float t2r = p1.x + p3.x, t2i = p1.y + p3.y;
        const float t3r = p1.x - p3.x, t3i = p1.y - p3.y;
        u4[bb][0] = make_float2(t0r + t2r, t0i + t2i);
        u4[bb][2] = make_float2(t0r - t2r, t0i - t2i);
        u4[bb][1] = make_float2(t1r - t3i, t1i + t3r);   // t1 + i*t3
        u4[bb][3] = make_float2(t1r + t3i, t1i - t3r);   // t1 - i*t3
      }
#pragma unroll
      for (int bb = 1; bb < 4; ++bb)
#pragma unroll
        for (int c = 1; c < 4; ++c)
          u4[bb][c] = cmulp(u4[bb][c], wtab[45 * (bb * c)]);   // W16^{bc}, bc<=9
      float2 g16[16];
#pragma unroll
      for (int c = 0; c < 4; ++c) {
        const float2 p0 = u4[0][c], p1 = u4[1][c], p2 = u4[2][c], p3 = u4[3][c];
        const float t0r = p0.x + p2.x, t0i = p0.y + p2.y;
        const float t1r = p0.x - p2.x, t1i = p0.y - p2.y;
        const float t2r = p1.x + p3.x, t2i = p1.y + p3.y;
        const float t3r = p1.x - p3.x, t3i = p1.y - p3.y;
        g16[c + 0]  = make_float2(t0r + t2r, t0i + t2i);
        g16[c + 8]  = make_float2(t0r - t2r, t0i - t2i);
        g16[c + 4]  = make_float2(t1r - t3i, t1i + t3r);
        g16[c + 12] = make_float2(t1r + t3i, t1i - t3r);
      }
#pragma unroll
      for (int k1 = 0; k1 < 16; ++k1)
        Yc[j * 720 + k1 * 45 + n2] = cmulp(g16[k1], wtab[n2 * k1]);   // W720^{n2*k1}
    }
    __syncthreads();

    // ---- stage 2: DFT-45 over n2 (9x5 CT), real part only -> cc. 256 tasks = (pair, k1, cq).
    {
      const int pr_ = tid >> 6;           // pair 0..3
      const int k1 = (tid >> 2) & 15;
      const int cq = tid & 3;
      const int nci = (cq == 0) ? 3 : 2;  // c in {cq, cq+4, cq+8(cq==0)}
      int cvals[3] = { cq, cq + 4, cq + 8 };
      const float2* Yrow = &Yc[pr_ * 720 + k1 * 45];

      float2 T9r[3][9], T45r[3][5];
#pragma unroll
      for (int ci = 0; ci < 3; ++ci) if (ci < nci) {
        const int c = cvals[ci];
#pragma unroll
        for (int a = 0; a < 9; ++a) T9r[ci][a] = t9[9 * a + c];
#pragma unroll
        for (int bq = 0; bq < 5; ++bq) T45r[ci][bq] = t45[9 * bq + c];
      }
      float2 w5[5];
#pragma unroll
      for (int m = 0; m < 5; ++m) w5[m] = wtab[144 * m];

      float yac[3][5];
#pragma unroll
      for (int ci = 0; ci < 3; ++ci)
#pragma unroll
        for (int d = 0; d < 5; ++d) yac[ci][d] = 0.f;

#pragma unroll
      for (int bq = 0; bq < 5; ++bq) {
        float2 z[9];
#pragma unroll
        for (int a = 0; a < 9; ++a) z[a] = Yrow[5 * a + bq];
#pragma unroll
        for (int ci = 0; ci < 3; ++ci) if (ci < nci) {
          float ur = 0.f, ui = 0.f;
#pragma unroll
          for (int a = 0; a < 9; ++a) {
            ur += z[a].x * T9r[ci][a].x - z[a].y * T9r[ci][a].y;
            ui += z[a].x * T9r[ci][a].y + z[a].y * T9r[ci][a].x;
          }
          const float2 tw = T45r[ci][bq];
          const float vr = ur * tw.x - ui * tw.y;
          const float vi = ur * tw.y + ui * tw.x;
#pragma unroll
          for (int d = 0; d < 5; ++d) {
            const int m = (bq * d) % 5;                     // compile-time
            yac[ci][d] += vr * w5[m].x - vi * w5[m].y;      // Re(v * W5^{bd})
          }
        }
      }
      float* ccF = (float*)Pc;   // overlay: row pr_ at stride CCSTRIDE floats
#pragma unroll
      for (int ci = 0; ci < 3; ++ci) if (ci < nci) {
        const int c = cvals[ci];
#pragma unroll
        for (int d = 0; d < 5; ++d)
          ccF[pr_ * CCSTRIDE + k1 + 16 * (c + 9 * d)] = yac[ci][d];
      }
    }
    __syncthreads();

    // ---- peak scans: 16 lanes per pair; semantics identical to verified time-domain version.
    if (tid < 64) {
      const int gq = tid >> 4, lane = tid & 15;
      const int c2 = c2base + 4 * ch + gq;
      const float* cr = (const float*)Pc + gq * CCSTRIDE;

      if (c2 >= c1) {     // forward pair (c1, c2)
        float bv = 0.f; int bt = 1;
        for (int i = lane; i < 718; i += 16) {
          const int t = i + 1;
          const float v = fabsf(cr[t]);
          const bool q = (v >= fabsf(cr[t - 1])) && (v >= fabsf(cr[t + 1]));
          const float cand = q ? v : 0.f;
          if (cand > bv || (cand == bv && t < bt)) { bv = cand; bt = t; }
        }
        for (int off = 8; off; off >>= 1) {
          const float ov = __shfl_down(bv, off, 16);
          const int ot = __shfl_down(bt, off, 16);
          if (ov > bv || (ov == bv && ot < bt)) { bv = ov; bt = ot; }
        }
        if (lane == 0) {
          const float r = (bv > 0.f) ? cr[bt] * SCALE : 0.f;
          const size_t o = ((size_t)(b * C_ + c1)) * C_ + c2;
          r_arr[o] = r; t_arr[o] = bt;
        }
      }
      if (c2 > c1) {      // mirrored pair (c2, c1): cc_m[t] = cc[(720-t)%720]
        float bv = 0.f; int bt = 1;
        for (int i = lane; i < 718; i += 16) {
          const int t = i + 1;
          const int u = 720 - t;
          const float v = fabsf(cr[u]);
          const float lft = fabsf(cr[(u == 719) ? 0 : (u + 1)]);
          const float rgt = fabsf(cr[u - 1]);
          const bool q = (v >= lft) && (v >= rgt);
          const float cand = q ? v : 0.f;
          if (cand > bv || (cand == bv && t < bt)) { bv = cand; bt = t; }
        }
        for (int off = 8; off; off >>= 1) {
          const float ov = __shfl_down(bv, off, 16);
          const int ot = __shfl_down(bt, off, 16);
          if (ov > bv || (ov == bv && ot < bt)) { bv = ov; bt = ot; }
        }
        if (lane == 0) {
          const float r = (bv > 0.f) ? cr[720 - bt] * SCALE : 0.f;
          const size_t o = ((size_t)(b * C_ + c2)) * C_ + c1;
          r_arr[o] = r; t_arr[o] = bt;
        }
      }
    }
    __syncthreads();   // cc (=Pc) reused by next chunk
  }
}

// ---------------------------------------------------------------- K3: top-k leaders, softmaxes, filt
__global__ __launch_bounds__(256) void k3_leaders(const float* __restrict__ x,
                                                  const float* __restrict__ temperature,
                                                  const float* __restrict__ cls_w,
                                                  const float* __restrict__ basic_state,
                                                  const float* __restrict__ state_bias,
                                                  const float* __restrict__ mhw,
                                                  const float* __restrict__ mhb,
                                                  const float* __restrict__ r_arr,
                                                  const int* __restrict__ t_arr,
                                                  int* __restrict__ lead_id,
                                                  int* __restrict__ lead_t,
                                                  float* __restrict__ lead_sr,
                                                  float* __restrict__ filt) {
  const int bc = blockIdx.x;
  const int b = bc >> 7, c = bc & 127;
  const int tid = threadIdx.x;
  __shared__ float caL[C_], rL[C_];
  __shared__ int tL[C_];
  __shared__ float cfL[K_], srL[K_], pL[S_], qL[S_ * K_], praw[S_];
  __shared__ int leadL[K_], ltL[K_];

  if (tid < C_) {
    const float r = r_arr[(size_t)bc * C_ + tid];
    rL[tid] = r; caL[tid] = fabsf(r);
    tL[tid] = t_arr[(size_t)bc * C_ + tid];
  }
  __syncthreads();

  if (tid == 0) {
    const float T = temperature[0];
    float lg[K_ + 1];
    lg[0] = 1.0f / T;
    for (int k = 0; k < K_; ++k) {       // stable top-k: strict > keeps smallest index on ties
      float bvv = -1.f; int bi = 0;
      for (int j = 0; j < C_; ++j) { const float v = caL[j]; if (v > bvv) { bvv = v; bi = j; } }
      leadL[k] = bi; ltL[k] = tL[bi];
      const float rv = rL[bi];
      srL[k] = (rv > 0.f) ? 1.f : ((rv < 0.f) ? -1.f : 0.f);
      lg[k + 1] = bvv / T;
      caL[bi] = -2.f;
    }
    float m = lg[0];
    for (int k = 1; k <= K_; ++k) m = fmaxf(m, lg[k]);
    float sum = 0.f, e[K_ + 1];
    for (int k = 0; k <= K_; ++k) { e[k] = expf(lg[k] - m); sum += e[k]; }
    const float invs = 1.0f / sum;
    for (int k = 0; k < K_; ++k) cfL[k] = e[k + 1] * invs;
  }
  __syncthreads();

  // p logits: 8 groups of 32 lanes, one state each
  {
    const int gg = tid >> 5, lane = tid & 31;
    float acc = 0.f;
    const float* xb = x + (size_t)b * L_ * C_ + c;
    const float* w = cls_w + (size_t)gg * L_;
    for (int l = lane; l < L_; l += 32) acc += xb[(size_t)l * C_] * w[l];
    for (int off = 16; off; off >>= 1) acc += __shfl_down(acc, off, 32);
    if (lane == 0) praw[gg] = acc + state_bias[gg] + basic_state[c * S_ + gg];
  }
  __syncthreads();
  if (tid == 0) {
    float m = praw[0];
    for (int s2 = 1; s2 < S_; ++s2) m = fmaxf(m, praw[s2]);
    float sum = 0.f;
    for (int s2 = 0; s2 < S_; ++s2) { const float e = expf(praw[s2] - m); pL[s2] = e; sum += e; }
    const float invs = 1.0f / sum;
    for (int s2 = 0; s2 < S_; ++s2) pL[s2] *= invs;
    for (int s2 = 0; s2 < S_; ++s2)
      for (int k = 0; k < K_; ++k) qL[s2 * K_ + k] = pL[s2] * cfL[k];
  }
  __syncthreads();

  for (int o = tid; o < OUT_; o += 256) {
    float acc = 0.f;
#pragma unroll
    for (int s2 = 0; s2 < S_; ++s2) {
      acc += pL[s2] * mhb[s2 * OUT_ + o];
#pragma unroll
      for (int k = 0; k < K_; ++k)
        acc += qL[s2 * K_ + k] * mhw[(size_t)s2 * (K_ * OUT_) + k * OUT_ + o];
    }
    filt[(size_t)bc * OUT_ + o] = acc;
  }
  if (tid < K_) {
    lead_id[bc * K_ + tid] = leadL[tid];
    lead_t[bc * K_ + tid] = ltL[tid];
    lead_sr[bc * K_ + tid] = srL[tid];
  }
}

// ---------------------------------------------------------------- K4: spectral mix + output
__global__ __launch_bounds__(256) void k4_final(const float* __restrict__ seq,
                                                const float* __restrict__ mu_g,
                                                const float* __restrict__ std_g,
                                                const int* __restrict__ lead_id,
                                                const int* __restrict__ lead_t,
                                                const float* __restrict__ lead_sr,
                                                const float* __restrict__ filt,
                                                const float* __restrict__ mwr,
                                                const float* __restrict__ mwi,
                                                const float* __restrict__ mbr,
                                                const float* __restrict__ mbi,
                                                float* __restrict__ out) {
  const int bc = blockIdx.x;
  const int b = bc >> 7, c = bc & 127;
  const int tid = threadIdx.x;
  __shared__ float cosT[96], sinT[96];
  __shared__ float ssL[K_][H_], ynL[H_], flL[OUT_];
  __shared__ float sfr[K_][F2_], sfi[K_][F2_], yfr[F2_], yfi[F2_];
  __shared__ float catr[3 * F2_], cati[3 * F2_], ofr[F2_], ofi[F2_];
  __shared__ int ldL[K_], ltL[K_];
  __shared__ float srL[K_];

  if (tid < 96) {
    const float ang = (float)tid * (float)(6.283185307179586 / 96.0);
    cosT[tid] = cosf(ang); sinT[tid] = sinf(ang);
    ynL[tid] = seq[(size_t)bc * SEQLEN + L_ + tid];
  }
  if (tid >= 96 && tid < 96 + K_) {
    const int k = tid - 96;
    ldL[k] = lead_id[bc * K_ + k];
    ltL[k] = lead_t[bc * K_ + k];
    srL[k] = lead_sr[bc * K_ + k];
  }
  for (int o = tid; o < OUT_; o += 256) flL[o] = filt[(size_t)bc * OUT_ + o];
  __syncthreads();

  for (int i = tid; i < K_ * H_; i += 256) {     // gather shifted leader windows
    const int k = i / H_, h = i - k * H_;
    ssL[k][h] = seq[((size_t)(b * C_ + ldL[k])) * SEQLEN + (L_ + h - ltL[k])] * srL[k];
  }
  __syncthreads();

  for (int u = tid; u < K_ * F2_ + F2_; u += 256) {    // 96-pt rfft (DFT) of ss rows and yn
    if (u < K_ * F2_) {
      const int k = u / F2_, f = u - k * F2_;
      float re = 0.f, im = 0.f; int m = 0;
      for (int h = 0; h < H_; ++h) {
        const float v = ssL[k][h];
        re = fmaf(v, cosT[m], re); im = fmaf(-v, sinT[m], im);
        m += f; if (m >= 96) m -= 96;
      }
      sfr[k][f] = re; sfi[k][f] = im;
    } else {
      const int f = u - K_ * F2_;
      float re = 0.f, im = 0.f; int m = 0;
      for (int h = 0; h < H_; ++h) {
        const float v = ynL[h];
        re = fmaf(v, cosT[m], re); im = fmaf(-v, sinT[m], im);
        m += f; if (m >= 96) m -= 96;
      }
      yfr[f] = re; yfi[f] = im;
    }
  }
  __syncthreads();

  if (tid < F2_) {
    const int f = tid;
    float s1r = 0.f, s1i = 0.f, s2r = 0.f, s2i = 0.f;
    const float yr = yfr[f], yi = yfi[f];
#pragma unroll
    for (int k = 0; k < K_; ++k) {
      const float fa = flL[k * F2_ + f], fb = flL[(K_ + k) * F2_ + f];
      const float ar = sfr[k][f] * fa, ai = sfi[k][f] * fa;
      s1r += ar; s1i += ai;
      s2r += (ar - yr) * fb; s2i += (ai - yi) * fb;
    }
    const float fc = flL[2 * K_ * F2_ + f];
    catr[f] = s1r;            cati[f] = s1i;
    catr[F2_ + f] = s2r;      cati[F2_ + f] = s2i;
    catr[2 * F2_ + f] = yr * fc; cati[2 * F2_ + f] = yi * fc;
  }
  __syncthreads();

  if (tid < F2_) {
    const int o = tid;
    float ar = mbr[o], ai = mbi[o];
    const float* wr = mwr + (size_t)o * (3 * F2_);
    const float* wi = mwi + (size_t)o * (3 * F2_);
    for (int f = 0; f < 3 * F2_; ++f) {
      const float cr = catr[f], ci = cati[f];
      const float wrr = wr[f], wii = wi[f];
      ar += cr * wrr - ci * wii;
      ai += cr * wii + ci * wrr;
    }
    ofr[o] = ar; ofi[o] = ai;
  }
  __syncthreads();

  if (tid < H_) {
    const int h = tid;
    float val = ofr[0] + ofr[48] * ((h & 1) ? -1.f : 1.f);
    int m = h;                                  // (f*h)%96 for f=1
    for (int f = 1; f < 48; ++f) {
      val += 2.f * (ofr[f] * cosT[m] - ofi[f] * sinT[m]);
      m += h; if (m >= 96) m -= 96;
    }
    val *= (1.0f / 96.0f);
    const float mu = mu_g[bc], stdv = std_g[bc];
    out[((size_t)b * H_ + h) * C_ + c] = (ynL[h] + val) * stdv + mu;
  }
}

// ---------------------------------------------------------------- launch
extern "C" void kernel_launch(void* const* d_in, const int* in_sizes, int n_in,
                              void* d_out, int out_size, void* d_ws, size_t ws_size,
                              hipStream_t stream) {
  const float* x    = (const float*)d_in[0];
  const float* yh   = (const float*)d_in[1];
  const float* temp = (const float*)d_in[2];
  const float* clsw = (const float*)d_in[3];
  const float* bst  = (const float*)d_in[4];
  const float* sbias= (const float*)d_in[5];
  const float* mhw  = (const float*)d_in[6];
  const float* mhb  = (const float*)d_in[7];
  const float* mwr  = (const float*)d_in[8];
  const float* mwi  = (const float*)d_in[9];
  const float* mbr  = (const float*)d_in[10];
  const float* mbi  = (const float*)d_in[11];
  float* out = (float*)d_out;

  float* ws = (float*)d_ws;
  float* seq    = ws;                                   // 2048*816
  float* mu_g   = seq + (size_t)2048 * SEQLEN;          // 2048
  float* std_g  = mu_g + 2048;                          // 2048
  float* r_arr  = std_g + 2048;                         // 262144
  float* filt   = r_arr + (size_t)2048 * C_;            // 2048*833
  int*   t_arr  = (int*)(filt + (size_t)2048 * OUT_);   // 262144
  int*   lead_i = t_arr + (size_t)2048 * C_;            // 16384
  int*   lead_t = lead_i + 2048 * K_;                   // 16384
  float* lead_s = (float*)(lead_t + 2048 * K_);         // 16384

  // Forward spectra alias the filt region (5.91 MB <= 6.82 MB):
  // k1f writes Rc -> k2 reads Rc -> k3 overwrites filt. Safe every replay.
  float2* Rc = (float2*)filt;

  hipLaunchKernelGGL(k1_norm, dim3(B_ * C_), dim3(256), 0, stream, x, yh, seq, mu_g, std_g);
  hipLaunchKernelGGL(k1f_fwd, dim3(B_ * C_), dim3(256), 0, stream, seq, Rc);
  hipLaunchKernelGGL(k2_fft, dim3(B_ * 576), dim3(256), 0, stream, Rc, r_arr, t_arr);
  hipLaunchKernelGGL(k3_leaders, dim3(B_ * C_), dim3(256), 0, stream,
                     x, temp, clsw, bst, sbias, mhw, mhb, r_arr, t_arr,
                     lead_i, lead_t, lead_s, filt);
  hipLaunchKernelGGL(k4_final, dim3(B_ * C_), dim3(256), 0, stream,
                     seq, mu_g, std_g, lead_i, lead_t, lead_s, filt,
                     mwr, mwi, mbr, mbi, out);
}

// Round 4
// 1445.502 us; speedup vs baseline: 2.9122x; 1.3191x over previous
//
#include <hip/hip_runtime.h>
#include <math.h>

#define B_ 16
#define L_ 720
#define C_ 128
#define H_ 96
#define F2_ 49
#define K_ 8
#define S_ 8
#define OUT_ 833          // F2*(2K+1)
#define SEQLEN 816        // L + H
#define NF 361            // rfft bins for L=720

__device__ __forceinline__ float2 cmulp(float2 a, float2 w) {   // a * w (complex)
  return make_float2(a.x*w.x - a.y*w.y, a.x*w.y + a.y*w.x);
}

// W16^{bc} = e^{+2*pi*i*bc/16}, indexed by bc in {1,2,3,4,6,9}
__device__ __constant__ float W16X[10] = {1.f, 0.9238795325112867f, 0.7071067811865476f, 0.3826834323650898f, 0.f, 0.f, -0.7071067811865476f, 0.f, 0.f, -0.9238795325112867f};
__device__ __constant__ float W16Y[10] = {0.f, 0.3826834323650898f, 0.7071067811865476f, 0.9238795325112867f, 1.f, 0.f, 0.7071067811865476f, 0.f, 0.f, -0.3826834323650898f};
// W5^m = e^{+2*pi*i*m/5}
__device__ __constant__ float W5X[5] = {1.f, 0.30901699437494742f, -0.80901699437494745f, -0.80901699437494745f, 0.30901699437494742f};
__device__ __constant__ float W5Y[5] = {0.f, 0.95105651629515357f, 0.58778525229247312f, -0.58778525229247312f, -0.95105651629515357f};

// ---------------------------------------------------------------- K0: twiddle table (once per launch)
__global__ __launch_bounds__(256) void k0_tab(float2* __restrict__ wtab_g) {
  for (int k = threadIdx.x; k < L_; k += 256) {
    double ang = (double)k * 0.008726646259971647884;   // 2*pi/720
    wtab_g[k] = make_float2((float)cos(ang), (float)sin(ang));
  }
}

// ---------------------------------------------------------------- K1: normalize
__global__ __launch_bounds__(256) void k1_norm(const float* __restrict__ x,
                                               const float* __restrict__ yh,
                                               float* __restrict__ seq,
                                               float* __restrict__ mu_g,
                                               float* __restrict__ std_g) {
  const int bc = blockIdx.x;            // b*C + c
  const int b = bc >> 7, c = bc & 127;
  const int tid = threadIdx.x;
  __shared__ float redA[4], redB[4];
  const float* xb = x + (size_t)b * L_ * C_ + c;   // element l at xb[l*C_]

  float s = 0.f;
  for (int l = tid; l < L_; l += 256) s += xb[(size_t)l * C_];
  for (int off = 32; off; off >>= 1) s += __shfl_down(s, off, 64);
  if ((tid & 63) == 0) redA[tid >> 6] = s;
  __syncthreads();
  const float mu = (redA[0] + redA[1] + redA[2] + redA[3]) * (1.0f / L_);

  float vs = 0.f;
  for (int l = tid; l < L_; l += 256) { float d = xb[(size_t)l * C_] - mu; vs += d * d; }
  for (int off = 32; off; off >>= 1) vs += __shfl_down(vs, off, 64);
  if ((tid & 63) == 0) redB[tid >> 6] = vs;
  __syncthreads();
  const float stdv = sqrtf((redB[0] + redB[1] + redB[2] + redB[3]) * (1.0f / L_) + 1e-8f);
  const float inv = 1.0f / stdv;

  float* sq = seq + (size_t)bc * SEQLEN;
  for (int l = tid; l < L_; l += 256) sq[l] = (xb[(size_t)l * C_] - mu) * inv;
  const float* yb = yh + (size_t)b * H_ * C_ + c;
  for (int h = tid; h < H_; h += 256) sq[L_ + h] = (yb[(size_t)h * C_] - mu) * inv;
  if (tid == 0) { mu_g[bc] = mu; std_g[bc] = stdv; }
}

// ---------------------------------------------------------------- K1f: forward rfft (naive DFT, negative exponent)
__global__ __launch_bounds__(256) void k1f_fwd(const float* __restrict__ seq,
                                               const float2* __restrict__ wtab_g,
                                               float2* __restrict__ Rc) {
  const int bc = blockIdx.x;
  const int tid = threadIdx.x;
  __shared__ float xrow[L_];
  __shared__ float2 wt[L_];
  for (int k = tid; k < L_; k += 256) {
    wt[k] = wtab_g[k];
    xrow[k] = seq[(size_t)bc * SEQLEN + k];
  }
  __syncthreads();
  for (int f = tid; f < NF; f += 256) {
    float re = 0.f, im = 0.f;
    int m = 0;
    for (int l = 0; l < L_; ++l) {
      const float v = xrow[l];
      const float2 w = wt[m];
      re = fmaf(v, w.x, re);
      im = fmaf(-v, w.y, im);
      m += f; if (m >= L_) m -= L_;
    }
    Rc[(size_t)bc * NF + f] = make_float2(re, im);
  }
}

// ---------------------------------------------------------------- K2: per-wave spectral product + 720-pt IFFT + peak pick
// cc[c1][c2][t] = cc[c2][c1][(L-t)%L] => triangle of 16-wide c2 tiles; emit fwd (c2>=c1) and mirror (c2>c1).
__global__ __launch_bounds__(256, 3) void k2_fft(const float2* __restrict__ Rc,
                                                 const float2* __restrict__ wtab_g,
                                                 float* __restrict__ r_arr,
                                                 int* __restrict__ t_arr) {
  // grid = B * 576; 576 = sum over tile-group g of 16*(8-g)
  int idx = blockIdx.x;
  const int b = idx / 576;
  idx -= b * 576;
  int g = 0;
  while (true) { const int cnt = (8 - g) << 4; if (idx < cnt) break; idx -= cnt; ++g; }
  const int rows = 8 - g;
  const int c1 = (g << 4) + idx / rows;
  const int c2t = g + idx % rows;
  const int c2base = c2t << 4;
  const int tid = threadIdx.x;
  const int wid = tid >> 6, lane = tid & 63;

  __shared__ float2 r1c[NF];
  __shared__ float2 t9[81];          // W9^{a*c} at [9a+c]
  __shared__ float2 t45[45];         // W45^{b*c} at [9b+c]
  __shared__ float2 R2w[4][NF];      // per-wave c2 spectrum
  __shared__ float2 Yw[4][720];      // per-wave stage-1 output, [k1*45+n2]
  __shared__ float  ccw[4][724];     // per-wave cc row

  for (int f = tid; f < NF; f += 256) r1c[f] = Rc[((size_t)(b * C_ + c1)) * NF + f];
  for (int i = tid; i < 81; i += 256) { int a = i / 9, c = i % 9; t9[i] = wtab_g[80 * ((a * c) % 9)]; }
  for (int i = tid; i < 45; i += 256) { int bb = i / 9, c = i % 9; t45[i] = wtab_g[16 * bb * c]; }
  __syncthreads();

  const float SCALE = 1.0f / 518400.0f;   // 1/720^2

  for (int j = 0; j < 4; ++j) {
    const int c2 = c2base + (wid << 2) + j;
    const float2* R2 = Rc + ((size_t)(b * C_ + c2)) * NF;
    for (int f = lane; f < NF; f += 64) R2w[wid][f] = R2[f];
    __syncthreads();

    // ---- stage 1: P on the fly + DFT-16 over n1 + exact twiddle. n = 45*n1+n2, k = k1+16*k2.
    if (lane < 45) {
      const int n2 = lane;
      float2 z[16];
#pragma unroll
      for (int n1 = 0; n1 < 16; ++n1) {
        const int fp = 45 * n1 + n2;
        const int f = (fp <= 360) ? fp : 720 - fp;
        const float2 a = r1c[f];
        const float2 v = R2w[wid][f];
        const float pr = a.x * v.x + a.y * v.y;
        float pi = a.y * v.x - a.x * v.y;
        if (fp > 360) pi = -pi;
        z[n1] = make_float2(pr, pi);
      }
      float2 u4[4][4];
#pragma unroll
      for (int bb = 0; bb < 4; ++bb) {
        const float2 p0 = z[bb], p1 = z[4 + bb], p2 = z[8 + bb], p3 = z[12 + bb];
        const float t0r = p0.x + p2.x, t0i = p0.y + p2.y;
        const float t1r = p0.x - p2.x, t1i = p0.y - p2.y;
        const float t2r = p1.x + p3.x, t2i = p1.y + p3.y;
        const float t3r = p1.x - p3.x, t3i = p1.y - p3.y;
        u4[bb][0] = make_float2(t0r + t2r, t0i + t2i);
        u4[bb][2] = make_float2(t0r - t2r, t0i - t2i);
        u4[bb][1] = make_float2(t1r - t3i, t1i + t3r);   // t1 + i*t3
        u4[bb][3] = make_float2(t1r + t3i, t1i - t3r);   // t1 - i*t3
      }
#pragma unroll
      for (int bb = 1; bb < 4; ++bb)
#pragma unroll
        for (int c = 1; c < 4; ++c) {
          const float2 w = make_float2(W16X[bb * c], W16Y[bb * c]);
          u4[bb][c] = cmulp(u4[bb][c], w);
        }
      float2 g16[16];
#pragma unroll
      for (int c = 0; c < 4; ++c) {
        const float2 p0 = u4[0][c], p1 = u4[1][c], p2 = u4[2][c], p3 = u4[3][c];
        const float t0r = p0.x + p2.x, t0i = p0.y + p2.y;
        const float t1r = p0.x - p2.x, t1i = p0.y - p2.y;
        const float t2r = p1.x + p3.x, t2i = p1.y + p3.y;
        const float t3r = p1.x - p3.x, t3i = p1.y - p3.y;
        g16[c + 0]  = make_float2(t0r + t2r, t0i + t2i);
        g16[c + 8]  = make_float2(t0r - t2r, t0i - t2i);
        g16[c + 4]  = make_float2(t1r - t3i, t1i + t3r);
        g16[c + 12] = make_float2(t1r + t3i, t1i - t3r);
      }
      int m = 0;
#pragma unroll
      for (int k1 = 0; k1 < 16; ++k1) {
        Yw[wid][k1 * 45 + n2] = cmulp(g16[k1], wtab_g[m]);   // exact W720^{n2*k1}
        m += n2; if (m >= 720) m -= 720;
      }
    }
    __syncthreads();

    // ---- stage 2: DFT-45 over n2 (9x5 CT), real part only. lane = k1*4 + cq.
    {
      const int k1 = lane >> 2;
      const int cq = lane & 3;
      const int nci = (cq == 0) ? 3 : 2;
      int cvals[3] = { cq, cq + 4, cq + 8 };
      const float2* Yrow = &Yw[wid][k1 * 45];

      float2 T9r[3][9], T45r[3][5];
#pragma unroll
      for (int ci = 0; ci < 3; ++ci) if (ci < nci) {
        const int c = cvals[ci];
#pragma unroll
        for (int a = 0; a < 9; ++a) T9r[ci][a] = t9[9 * a + c];
#pragma unroll
        for (int bq = 0; bq < 5; ++bq) T45r[ci][bq] = t45[9 * bq + c];
      }

      float yac[3][5];
#pragma unroll
      for (int ci = 0; ci < 3; ++ci)
#pragma unroll
        for (int d = 0; d < 5; ++d) yac[ci][d] = 0.f;

#pragma unroll
      for (int bq = 0; bq < 5; ++bq) {
        float2 z[9];
#pragma unroll
        for (int a = 0; a < 9; ++a) z[a] = Yrow[5 * a + bq];
#pragma unroll
        for (int ci = 0; ci < 3; ++ci) if (ci < nci) {
          float ur = 0.f, ui = 0.f;
#pragma unroll
          for (int a = 0; a < 9; ++a) {
            ur += z[a].x * T9r[ci][a].x - z[a].y * T9r[ci][a].y;
            ui += z[a].x * T9r[ci][a].y + z[a].y * T9r[ci][a].x;
          }
          const float2 tw = T45r[ci][bq];
          const float vr = ur * tw.x - ui * tw.y;
          const float vi = ur * tw.y + ui * tw.x;
#pragma unroll
          for (int d = 0; d < 5; ++d) {
            const int m = (bq * d) % 5;                   // compile-time
            yac[ci][d] += vr * W5X[m] - vi * W5Y[m];      // Re(v * W5^{bd})
          }
        }
      }
#pragma unroll
      for (int ci = 0; ci < 3; ++ci) if (ci < nci) {
        const int c = cvals[ci];
#pragma unroll
        for (int d = 0; d < 5; ++d)
          ccw[wid][k1 + 16 * (c + 9 * d)] = yac[ci][d];
      }
    }
    __syncthreads();

    // ---- peak scans: full wave per row; semantics identical to verified versions.
    const float* cr = ccw[wid];
    if (c2 >= c1) {     // forward pair (c1, c2)
      float bv = 0.f; int bt = 1;
      for (int i = lane; i < 718; i += 64) {
        const int t = i + 1;
        const float v = fabsf(cr[t]);
        const bool q = (v >= fabsf(cr[t - 1])) && (v >= fabsf(cr[t + 1]));
        const float cand = q ? v : 0.f;
        if (cand > bv || (cand == bv && t < bt)) { bv = cand; bt = t; }
      }
      for (int off = 32; off; off >>= 1) {
        const float ov = __shfl_down(bv, off, 64);
        const int ot = __shfl_down(bt, off, 64);
        if (ov > bv || (ov == bv && ot < bt)) { bv = ov; bt = ot; }
      }
      if (lane == 0) {
        const float r = (bv > 0.f) ? cr[bt] * SCALE : 0.f;
        const size_t o = ((size_t)(b * C_ + c1)) * C_ + c2;
        r_arr[o] = r; t_arr[o] = bt;
      }
    }
    if (c2 > c1) {      // mirrored pair (c2, c1): cc_m[t] = cc[(720-t)%720]
      float bv = 0.f; int bt = 1;
      for (int i = lane; i < 718; i += 64) {
        const int t = i + 1;
        const int u = 720 - t;
        const float v = fabsf(cr[u]);
        const float lft = fabsf(cr[(u == 719) ? 0 : (u + 1)]);
        const float rgt = fabsf(cr[u - 1]);
        const bool q = (v >= lft) && (v >= rgt);
        const float cand = q ? v : 0.f;
        if (cand > bv || (cand == bv && t < bt)) { bv = cand; bt = t; }
      }
      for (int off = 32; off; off >>= 1) {
        const float ov = __shfl_down(bv, off, 64);
        const int ot = __shfl_down(bt, off, 64);
        if (ov > bv || (ov == bv && ot < bt)) { bv = ov; bt = ot; }
      }
      if (lane == 0) {
        const float r = (bv > 0.f) ? cr[720 - bt] * SCALE : 0.f;
        const size_t o = ((size_t)(b * C_ + c2)) * C_ + c1;
        r_arr[o] = r; t_arr[o] = bt;
      }
    }
    __syncthreads();   // buffers reused next pair
  }
}

// ---------------------------------------------------------------- K3: top-k leaders, softmaxes, filt
__global__ __launch_bounds__(256) void k3_leaders(const float* __restrict__ x,
                                                  const float* __restrict__ temperature,
                                                  const float* __restrict__ cls_w,
                                                  const float* __restrict__ basic_state,
                                                  const float* __restrict__ state_bias,
                                                  const float* __restrict__ mhw,
                                                  const float* __restrict__ mhb,
                                                  const float* __restrict__ r_arr,
                                                  const int* __restrict__ t_arr,
                                                  int* __restrict__ lead_id,
                                                  int* __restrict__ lead_t,
                                                  float* __restrict__ lead_sr,
                                                  float* __restrict__ filt) {
  const int bc = blockIdx.x;
  const int b = bc >> 7, c = bc & 127;
  const int tid = threadIdx.x;
  __shared__ float caL[C_], rL[C_];
  __shared__ int tL[C_];
  __shared__ float xrowL[L_];
  __shared__ float cfL[K_], srL[K_], pL[S_], qL[S_ * K_], praw[S_];
  __shared__ int leadL[K_], ltL[K_];

  const float* xb = x + (size_t)b * L_ * C_ + c;
  for (int l = tid; l < L_; l += 256) xrowL[l] = xb[(size_t)l * C_];
  if (tid < C_) {
    const float r = r_arr[(size_t)bc * C_ + tid];
    rL[tid] = r; caL[tid] = fabsf(r);
    tL[tid] = t_arr[(size_t)bc * C_ + tid];
  }
  __syncthreads();

  if (tid == 0) {
    const float T = temperature[0];
    float lg[K_ + 1];
    lg[0] = 1.0f / T;
    for (int k = 0; k < K_; ++k) {       // stable top-k: strict > keeps smallest index on ties
      float bvv = -1.f; int bi = 0;
      for (int jj = 0; jj < C_; ++jj) { const float v = caL[jj]; if (v > bvv) { bvv = v; bi = jj; } }
      leadL[k] = bi; ltL[k] = tL[bi];
      const float rv = rL[bi];
      srL[k] = (rv > 0.f) ? 1.f : ((rv < 0.f) ? -1.f : 0.f);
      lg[k + 1] = bvv / T;
      caL[bi] = -2.f;
    }
    float m = lg[0];
    for (int k = 1; k <= K_; ++k) m = fmaxf(m, lg[k]);
    float sum = 0.f, e[K_ + 1];
    for (int k = 0; k <= K_; ++k) { e[k] = expf(lg[k] - m); sum += e[k]; }
    const float invs = 1.0f / sum;
    for (int k = 0; k < K_; ++k) cfL[k] = e[k + 1] * invs;
  }
  __syncthreads();

  // p logits: 8 groups of 32 lanes, one state each
  {
    const int gg = tid >> 5, lane = tid & 31;
    float acc = 0.f;
    const float* w = cls_w + (size_t)gg * L_;
    for (int l = lane; l < L_; l += 32) acc += xrowL[l] * w[l];
    for (int off = 16; off; off >>= 1) acc += __shfl_down(acc, off, 32);
    if (lane == 0) praw[gg] = acc + state_bias[gg] + basic_state[c * S_ + gg];
  }
  __syncthreads();
  if (tid == 0) {
    float m = praw[0];
    for (int s2 = 1; s2 < S_; ++s2) m = fmaxf(m, praw[s2]);
    float sum = 0.f;
    for (int s2 = 0; s2 < S_; ++s2) { const float e = expf(praw[s2] - m); pL[s2] = e; sum += e; }
    const float invs = 1.0f / sum;
    for (int s2 = 0; s2 < S_; ++s2) pL[s2] *= invs;
    for (int s2 = 0; s2 < S_; ++s2)
      for (int k = 0; k < K_; ++k) qL[s2 * K_ + k] = pL[s2] * cfL[k];
  }
  __syncthreads();

  for (int o = tid; o < OUT_; o += 256) {
    float acc = 0.f;
#pragma unroll
    for (int s2 = 0; s2 < S_; ++s2) {
      acc += pL[s2] * mhb[s2 * OUT_ + o];
#pragma unroll
      for (int k = 0; k < K_; ++k)
        acc += qL[s2 * K_ + k] * mhw[(size_t)s2 * (K_ * OUT_) + k * OUT_ + o];
    }
    filt[(size_t)bc * OUT_ + o] = acc;
  }
  if (tid < K_) {
    lead_id[bc * K_ + tid] = leadL[tid];
    lead_t[bc * K_ + tid] = ltL[tid];
    lead_sr[bc * K_ + tid] = srL[tid];
  }
}

// ---------------------------------------------------------------- K4: spectral mix + output
__global__ __launch_bounds__(256) void k4_final(const float* __restrict__ seq,
                                                const float* __restrict__ mu_g,
                                                const float* __restrict__ std_g,
                                                const int* __restrict__ lead_id,
                                                const int* __restrict__ lead_t,
                                                const float* __restrict__ lead_sr,
                                                const float* __restrict__ filt,
                                                const float* __restrict__ mwr,
                                                const float* __restrict__ mwi,
                                                const float* __restrict__ mbr,
                                                const float* __restrict__ mbi,
                                                float* __restrict__ out) {
  const int bc = blockIdx.x;
  const int b = bc >> 7, c = bc & 127;
  const int tid = threadIdx.x;
  __shared__ float cosT[96], sinT[96];
  __shared__ float ssL[K_][H_], ynL[H_], flL[OUT_];
  __shared__ float sfr[K_][F2_], sfi[K_][F2_], yfr[F2_], yfi[F2_];
  __shared__ float catr[3 * F2_], cati[3 * F2_], ofr[F2_], ofi[F2_];
  __shared__ int ldL[K_], ltL[K_];
  __shared__ float srL[K_];

  if (tid < 96) {
    const float ang = (float)tid * (float)(6.283185307179586 / 96.0);
    cosT[tid] = cosf(ang); sinT[tid] = sinf(ang);
    ynL[tid] = seq[(size_t)bc * SEQLEN + L_ + tid];
  }
  if (tid >= 96 && tid < 96 + K_) {
    const int k = tid - 96;
    ldL[k] = lead_id[bc * K_ + k];
    ltL[k] = lead_t[bc * K_ + k];
    srL[k] = lead_sr[bc * K_ + k];
  }
  for (int o = tid; o < OUT_; o += 256) flL[o] = filt[(size_t)bc * OUT_ + o];
  __syncthreads();

  for (int i = tid; i < K_ * H_; i += 256) {     // gather shifted leader windows
    const int k = i / H_, h = i - k * H_;
    ssL[k][h] = seq[((size_t)(b * C_ + ldL[k])) * SEQLEN + (L_ + h - ltL[k])] * srL[k];
  }
  __syncthreads();

  for (int u = tid; u < K_ * F2_ + F2_; u += 256) {    // 96-pt rfft (DFT) of ss rows and yn
    if (u < K_ * F2_) {
      const int k = u / F2_, f = u - k * F2_;
      float re = 0.f, im = 0.f; int m = 0;
      for (int h = 0; h < H_; ++h) {
        const float v = ssL[k][h];
        re = fmaf(v, cosT[m], re); im = fmaf(-v, sinT[m], im);
        m += f; if (m >= 96) m -= 96;
      }
      sfr[k][f] = re; sfi[k][f] = im;
    } else {
      const int f = u - K_ * F2_;
      float re = 0.f, im = 0.f; int m = 0;
      for (int h = 0; h < H_; ++h) {
        const float v = ynL[h];
        re = fmaf(v, cosT[m], re); im = fmaf(-v, sinT[m], im);
        m += f; if (m >= 96) m -= 96;
      }
      yfr[f] = re; yfi[f] = im;
    }
  }
  __syncthreads();

  if (tid < F2_) {
    const int f = tid;
    float s1r = 0.f, s1i = 0.f, s2r = 0.f, s2i = 0.f;
    const float yr = yfr[f], yi = yfi[f];
#pragma unroll
    for (int k = 0; k < K_; ++k) {
      const float fa = flL[k * F2_ + f], fb = flL[(K_ + k) * F2_ + f];
      const float ar = sfr[k][f] * fa, ai = sfi[k][f] * fa;
      s1r += ar; s1i += ai;
      s2r += (ar - yr) * fb; s2i += (ai - yi) * fb;
    }
    const float fc = flL[2 * K_ * F2_ + f];
    catr[f] = s1r;            cati[f] = s1i;
    catr[F2_ + f] = s2r;      cati[F2_ + f] = s2i;
    catr[2 * F2_ + f] = yr * fc; cati[2 * F2_ + f] = yi * fc;
  }
  __syncthreads();

  if (tid < F2_) {
    const int o = tid;
    float ar = mbr[o], ai = mbi[o];
    const float* wr = mwr + (size_t)o * (3 * F2_);
    const float* wi = mwi + (size_t)o * (3 * F2_);
    for (int f = 0; f < 3 * F2_; ++f) {
      const float cr = catr[f], ci = cati[f];
      const float wrr = wr[f], wii = wi[f];
      ar += cr * wrr - ci * wii;
      ai += cr * wii + ci * wrr;
    }
    ofr[o] = ar; ofi[o] = ai;
  }
  __syncthreads();

  if (tid < H_) {
    const int h = tid;
    float val = ofr[0] + ofr[48] * ((h & 1) ? -1.f : 1.f);
    int m = h;                                  // (f*h)%96 for f=1
    for (int f = 1; f < 48; ++f) {
      val += 2.f * (ofr[f] * cosT[m] - ofi[f] * sinT[m]);
      m += h; if (m >= 96) m -= 96;
    }
    val *= (1.0f / 96.0f);
    const float mu = mu_g[bc], stdv = std_g[bc];
    out[((size_t)b * H_ + h) * C_ + c] = (ynL[h] + val) * stdv + mu;
  }
}

// ---------------------------------------------------------------- launch
extern "C" void kernel_launch(void* const* d_in, const int* in_sizes, int n_in,
                              void* d_out, int out_size, void* d_ws, size_t ws_size,
                              hipStream_t stream) {
  const float* x    = (const float*)d_in[0];
  const float* yh   = (const float*)d_in[1];
  const float* temp = (const float*)d_in[2];
  const float* clsw = (const float*)d_in[3];
  const float* bst  = (const float*)d_in[4];
  const float* sbias= (const float*)d_in[5];
  const float* mhw  = (const float*)d_in[6];
  const float* mhb  = (const float*)d_in[7];
  const float* mwr  = (const float*)d_in[8];
  const float* mwi  = (const float*)d_in[9];
  const float* mbr  = (const float*)d_in[10];
  const float* mbi  = (const float*)d_in[11];
  float* out = (float*)d_out;

  float* ws = (float*)d_ws;
  float* seq    = ws;                                   // 2048*816
  float* mu_g   = seq + (size_t)2048 * SEQLEN;          // 2048
  float* std_g  = mu_g + 2048;                          // 2048
  float* r_arr  = std_g + 2048;                         // 262144
  float* filt   = r_arr + (size_t)2048 * C_;            // 2048*833
  int*   t_arr  = (int*)(filt + (size_t)2048 * OUT_);   // 262144
  int*   lead_i = t_arr + (size_t)2048 * C_;            // 16384
  int*   lead_t = lead_i + 2048 * K_;                   // 16384
  float* lead_s = (float*)(lead_t + 2048 * K_);         // 16384
  float2* wtab  = (float2*)(lead_s + 2048 * K_);        // 720 float2

  // Forward spectra alias the filt region (5.91 MB <= 6.82 MB):
  // k1f writes Rc -> k2 reads Rc -> k3 overwrites filt. Safe every replay.
  float2* Rc = (float2*)filt;

  hipLaunchKernelGGL(k0_tab, dim3(1), dim3(256), 0, stream, wtab);
  hipLaunchKernelGGL(k1_norm, dim3(B_ * C_), dim3(256), 0, stream, x, yh, seq, mu_g, std_g);
  hipLaunchKernelGGL(k1f_fwd, dim3(B_ * C_), dim3(256), 0, stream, seq, wtab, Rc);
  hipLaunchKernelGGL(k2_fft, dim3(B_ * 576), dim3(256), 0, stream, Rc, wtab, r_arr, t_arr);
  hipLaunchKernelGGL(k3_leaders, dim3(B_ * C_), dim3(256), 0, stream,
                     x, temp, clsw, bst, sbias, mhw, mhb, r_arr, t_arr,
                     lead_i, lead_t, lead_s, filt);
  hipLaunchKernelGGL(k4_final, dim3(B_ * C_), dim3(256), 0, stream,
                     seq, mu_g, std_g, lead_i, lead_t, lead_s, filt,
                     mwr, mwi, mbr, mbi, out);
}

// Round 5
// 1125.395 us; speedup vs baseline: 3.7406x; 1.2844x over previous
//
#include <hip/hip_runtime.h>
#include <math.h>

#define B_ 16
#define L_ 720
#define C_ 128
#define H_ 96
#define F2_ 49
#define K_ 8
#define S_ 8
#define OUT_ 833          // F2*(2K+1)
#define SEQLEN 816        // L + H
#define NF 361            // rfft bins for L=720

__device__ __forceinline__ float2 cmulp(float2 a, float2 w) {   // a * w (complex)
  return make_float2(a.x*w.x - a.y*w.y, a.x*w.y + a.y*w.x);
}

// W16^{bc} = e^{+2*pi*i*bc/16}, indexed by bc in {1,2,3,4,6,9}
__device__ __constant__ float W16X[10] = {1.f, 0.9238795325112867f, 0.7071067811865476f, 0.3826834323650898f, 0.f, 0.f, -0.7071067811865476f, 0.f, 0.f, -0.9238795325112867f};
__device__ __constant__ float W16Y[10] = {0.f, 0.3826834323650898f, 0.7071067811865476f, 0.9238795325112867f, 1.f, 0.f, 0.7071067811865476f, 0.f, 0.f, -0.3826834323650898f};
// W5^m = e^{+2*pi*i*m/5}
__device__ __constant__ float W5X[5] = {1.f, 0.30901699437494742f, -0.80901699437494745f, -0.80901699437494745f, 0.30901699437494742f};
__device__ __constant__ float W5Y[5] = {0.f, 0.95105651629515357f, 0.58778525229247312f, -0.58778525229247312f, -0.95105651629515357f};

// ---------------------------------------------------------------- K0: twiddle table (once per launch)
__global__ __launch_bounds__(256) void k0_tab(float2* __restrict__ wtab_g) {
  for (int k = threadIdx.x; k < L_; k += 256) {
    double ang = (double)k * 0.008726646259971647884;   // 2*pi/720
    wtab_g[k] = make_float2((float)cos(ang), (float)sin(ang));
  }
}

// ---------------------------------------------------------------- K1: normalize
__global__ __launch_bounds__(256) void k1_norm(const float* __restrict__ x,
                                               const float* __restrict__ yh,
                                               float* __restrict__ seq,
                                               float* __restrict__ mu_g,
                                               float* __restrict__ std_g) {
  const int bc = blockIdx.x;            // b*C + c
  const int b = bc >> 7, c = bc & 127;
  const int tid = threadIdx.x;
  __shared__ float redA[4], redB[4];
  const float* xb = x + (size_t)b * L_ * C_ + c;   // element l at xb[l*C_]

  float s = 0.f;
  for (int l = tid; l < L_; l += 256) s += xb[(size_t)l * C_];
  for (int off = 32; off; off >>= 1) s += __shfl_down(s, off, 64);
  if ((tid & 63) == 0) redA[tid >> 6] = s;
  __syncthreads();
  const float mu = (redA[0] + redA[1] + redA[2] + redA[3]) * (1.0f / L_);

  float vs = 0.f;
  for (int l = tid; l < L_; l += 256) { float d = xb[(size_t)l * C_] - mu; vs += d * d; }
  for (int off = 32; off; off >>= 1) vs += __shfl_down(vs, off, 64);
  if ((tid & 63) == 0) redB[tid >> 6] = vs;
  __syncthreads();
  const float stdv = sqrtf((redB[0] + redB[1] + redB[2] + redB[3]) * (1.0f / L_) + 1e-8f);
  const float inv = 1.0f / stdv;

  float* sq = seq + (size_t)bc * SEQLEN;
  for (int l = tid; l < L_; l += 256) sq[l] = (xb[(size_t)l * C_] - mu) * inv;
  const float* yb = yh + (size_t)b * H_ * C_ + c;
  for (int h = tid; h < H_; h += 256) sq[L_ + h] = (yb[(size_t)h * C_] - mu) * inv;
  if (tid == 0) { mu_g[bc] = mu; std_g[bc] = stdv; }
}

// ---------------------------------------------------------------- K1f: forward rfft (naive DFT, negative exponent)
__global__ __launch_bounds__(256) void k1f_fwd(const float* __restrict__ seq,
                                               const float2* __restrict__ wtab_g,
                                               float2* __restrict__ Rc) {
  const int bc = blockIdx.x;
  const int tid = threadIdx.x;
  __shared__ float xrow[L_];
  __shared__ float2 wt[L_];
  for (int k = tid; k < L_; k += 256) {
    wt[k] = wtab_g[k];
    xrow[k] = seq[(size_t)bc * SEQLEN + k];
  }
  __syncthreads();
  for (int f = tid; f < NF; f += 256) {
    float re = 0.f, im = 0.f;
    int m = 0;
    for (int l = 0; l < L_; ++l) {
      const float v = xrow[l];
      const float2 w = wt[m];
      re = fmaf(v, w.x, re);
      im = fmaf(-v, w.y, im);
      m += f; if (m >= L_) m -= L_;
    }
    Rc[(size_t)bc * NF + f] = make_float2(re, im);
  }
}

// ---------------------------------------------------------------- K2: per-wave spectral product + 720-pt IFFT + peak pick
// cc[c1][c2][t] = cc[c2][c1][(L-t)%L] => triangle of 16-wide c2 tiles; emit fwd (c2>=c1) and mirror (c2>c1).
__global__ __launch_bounds__(256, 2) void k2_fft(const float2* __restrict__ Rc,
                                                 const float2* __restrict__ wtab_g,
                                                 float* __restrict__ r_arr,
                                                 int* __restrict__ t_arr) {
  // grid = B * 576; 576 = sum over tile-group g of 16*(8-g)
  int idx = blockIdx.x;
  const int b = idx / 576;
  idx -= b * 576;
  int g = 0;
  while (true) { const int cnt = (8 - g) << 4; if (idx < cnt) break; idx -= cnt; ++g; }
  const int rows = 8 - g;
  const int c1 = (g << 4) + idx / rows;
  const int c2t = g + idx % rows;
  const int c2base = c2t << 4;
  const int tid = threadIdx.x;
  const int wid = tid >> 6, lane = tid & 63;

  __shared__ float2 r1c[NF];
  __shared__ float2 t9[81];          // W9^{a*c} at [9a+c]
  __shared__ float2 t45[45];         // W45^{b*c} at [9b+c]
  __shared__ float2 R2w[4][NF];      // per-wave c2 spectrum
  __shared__ float2 Yw[4][720];      // per-wave stage-1 output, [k1*45+n2]
  __shared__ float  ccw[4][724];     // per-wave cc row

  for (int f = tid; f < NF; f += 256) r1c[f] = Rc[((size_t)(b * C_ + c1)) * NF + f];
  for (int i = tid; i < 81; i += 256) { int a = i / 9, c = i % 9; t9[i] = wtab_g[80 * ((a * c) % 9)]; }
  for (int i = tid; i < 45; i += 256) { int bb = i / 9, c = i % 9; t45[i] = wtab_g[16 * bb * c]; }
  __syncthreads();

  const float SCALE = 1.0f / 518400.0f;   // 1/720^2

  for (int j = 0; j < 4; ++j) {
    const int c2 = c2base + (wid << 2) + j;
    const float2* R2 = Rc + ((size_t)(b * C_ + c2)) * NF;
    for (int f = lane; f < NF; f += 64) R2w[wid][f] = R2[f];
    __syncthreads();

    // ---- stage 1: P on the fly + DFT-16 over n1 + exact twiddle. n = 45*n1+n2, k = k1+16*k2.
    if (lane < 45) {
      const int n2 = lane;
      float2 u4[4][4];
#pragma unroll
      for (int bb = 0; bb < 4; ++bb) {
        float2 zz[4];                                  // z[4q+bb], chunked to cap pressure
#pragma unroll
        for (int q = 0; q < 4; ++q) {
          const int fp = 45 * (4 * q + bb) + n2;
          const int f = (fp <= 360) ? fp : 720 - fp;
          const float2 a = r1c[f];
          const float2 v = R2w[wid][f];
          const float pr = a.x * v.x + a.y * v.y;
          float pi = a.y * v.x - a.x * v.y;
          if (fp > 360) pi = -pi;
          zz[q] = make_float2(pr, pi);
        }
        const float t0r = zz[0].x + zz[2].x, t0i = zz[0].y + zz[2].y;
        const float t1r = zz[0].x - zz[2].x, t1i = zz[0].y - zz[2].y;
        const float t2r = zz[1].x + zz[3].x, t2i = zz[1].y + zz[3].y;
        const float t3r = zz[1].x - zz[3].x, t3i = zz[1].y - zz[3].y;
        u4[bb][0] = make_float2(t0r + t2r, t0i + t2i);
        u4[bb][2] = make_float2(t0r - t2r, t0i - t2i);
        u4[bb][1] = make_float2(t1r - t3i, t1i + t3r);   // t1 + i*t3
        u4[bb][3] = make_float2(t1r + t3i, t1i - t3r);   // t1 - i*t3
      }
#pragma unroll
      for (int bb = 1; bb < 4; ++bb)
#pragma unroll
        for (int c = 1; c < 4; ++c) {
          const float2 w = make_float2(W16X[bb * c], W16Y[bb * c]);
          u4[bb][c] = cmulp(u4[bb][c], w);
        }
      float2 g16[16];
#pragma unroll
      for (int c = 0; c < 4; ++c) {
        const float2 p0 = u4[0][c], p1 = u4[1][c], p2 = u4[2][c], p3 = u4[3][c];
        const float t0r = p0.x + p2.x, t0i = p0.y + p2.y;
        const float t1r = p0.x - p2.x, t1i = p0.y - p2.y;
        const float t2r = p1.x + p3.x, t2i = p1.y + p3.y;
        const float t3r = p1.x - p3.x, t3i = p1.y - p3.y;
        g16[c + 0]  = make_float2(t0r + t2r, t0i + t2i);
        g16[c + 8]  = make_float2(t0r - t2r, t0i - t2i);
        g16[c + 4]  = make_float2(t1r - t3i, t1i + t3r);
        g16[c + 12] = make_float2(t1r + t3i, t1i - t3r);
      }
      int m = 0;
#pragma unroll
      for (int k1 = 0; k1 < 16; ++k1) {
        Yw[wid][k1 * 45 + n2] = cmulp(g16[k1], wtab_g[m]);   // exact W720^{n2*k1}
        m += n2; if (m >= 720) m -= 720;
      }
    }
    __syncthreads();

    // ---- stage 2: DFT-45 over n2 (9x5 CT), real part only. lane = k1*4 + cq.
    {
      const int k1 = lane >> 2;
      const int cq = lane & 3;
      const int nci = (cq == 0) ? 3 : 2;
      int cvals[3] = { cq, cq + 4, cq + 8 };
      const float2* Yrow = &Yw[wid][k1 * 45];

      float2 T9r[3][9], T45r[3][5];
#pragma unroll
      for (int ci = 0; ci < 3; ++ci) if (ci < nci) {
        const int c = cvals[ci];
#pragma unroll
        for (int a = 0; a < 9; ++a) T9r[ci][a] = t9[9 * a + c];
#pragma unroll
        for (int bq = 0; bq < 5; ++bq) T45r[ci][bq] = t45[9 * bq + c];
      }

      float yac[3][5];
#pragma unroll
      for (int ci = 0; ci < 3; ++ci)
#pragma unroll
        for (int d = 0; d < 5; ++d) yac[ci][d] = 0.f;

#pragma unroll
      for (int bq = 0; bq < 5; ++bq) {
        float2 z[9];
#pragma unroll
        for (int a = 0; a < 9; ++a) z[a] = Yrow[5 * a + bq];
#pragma unroll
        for (int ci = 0; ci < 3; ++ci) if (ci < nci) {
          float ur = 0.f, ui = 0.f;
#pragma unroll
          for (int a = 0; a < 9; ++a) {
            ur += z[a].x * T9r[ci][a].x - z[a].y * T9r[ci][a].y;
            ui += z[a].x * T9r[ci][a].y + z[a].y * T9r[ci][a].x;
          }
          const float2 tw = T45r[ci][bq];
          const float vr = ur * tw.x - ui * tw.y;
          const float vi = ur * tw.y + ui * tw.x;
#pragma unroll
          for (int d = 0; d < 5; ++d) {
            const int m = (bq * d) % 5;                   // compile-time
            yac[ci][d] += vr * W5X[m] - vi * W5Y[m];      // Re(v * W5^{bd})
          }
        }
      }
#pragma unroll
      for (int ci = 0; ci < 3; ++ci) if (ci < nci) {
        const int c = cvals[ci];
#pragma unroll
        for (int d = 0; d < 5; ++d)
          ccw[wid][k1 + 16 * (c + 9 * d)] = yac[ci][d];
      }
    }
    __syncthreads();

    // ---- peak scans: full wave per row; semantics identical to verified versions.
    const float* cr = ccw[wid];
    if (c2 >= c1) {     // forward pair (c1, c2)
      float bv = 0.f; int bt = 1;
      for (int i = lane; i < 718; i += 64) {
        const int t = i + 1;
        const float v = fabsf(cr[t]);
        const bool q = (v >= fabsf(cr[t - 1])) && (v >= fabsf(cr[t + 1]));
        const float cand = q ? v : 0.f;
        if (cand > bv || (cand == bv && t < bt)) { bv = cand; bt = t; }
      }
      for (int off = 32; off; off >>= 1) {
        const float ov = __shfl_down(bv, off, 64);
        const int ot = __shfl_down(bt, off, 64);
        if (ov > bv || (ov == bv && ot < bt)) { bv = ov; bt = ot; }
      }
      if (lane == 0) {
        const float r = (bv > 0.f) ? cr[bt] * SCALE : 0.f;
        const size_t o = ((size_t)(b * C_ + c1)) * C_ + c2;
        r_arr[o] = r; t_arr[o] = bt;
      }
    }
    if (c2 > c1) {      // mirrored pair (c2, c1): cc_m[t] = cc[(720-t)%720]
      float bv = 0.f; int bt = 1;
      for (int i = lane; i < 718; i += 64) {
        const int t = i + 1;
        const int u = 720 - t;
        const float v = fabsf(cr[u]);
        const float lft = fabsf(cr[(u == 719) ? 0 : (u + 1)]);
        const float rgt = fabsf(cr[u - 1]);
        const bool q = (v >= lft) && (v >= rgt);
        const float cand = q ? v : 0.f;
        if (cand > bv || (cand == bv && t < bt)) { bv = cand; bt = t; }
      }
      for (int off = 32; off; off >>= 1) {
        const float ov = __shfl_down(bv, off, 64);
        const int ot = __shfl_down(bt, off, 64);
        if (ov > bv || (ov == bv && ot < bt)) { bv = ov; bt = ot; }
      }
      if (lane == 0) {
        const float r = (bv > 0.f) ? cr[720 - bt] * SCALE : 0.f;
        const size_t o = ((size_t)(b * C_ + c2)) * C_ + c1;
        r_arr[o] = r; t_arr[o] = bt;
      }
    }
    __syncthreads();   // buffers reused next pair
  }
}

// ---------------------------------------------------------------- K3: top-k leaders, softmaxes, filt
__global__ __launch_bounds__(256) void k3_leaders(const float* __restrict__ x,
                                                  const float* __restrict__ temperature,
                                                  const float* __restrict__ cls_w,
                                                  const float* __restrict__ basic_state,
                                                  const float* __restrict__ state_bias,
                                                  const float* __restrict__ mhw,
                                                  const float* __restrict__ mhb,
                                                  const float* __restrict__ r_arr,
                                                  const int* __restrict__ t_arr,
                                                  int* __restrict__ lead_id,
                                                  int* __restrict__ lead_t,
                                                  float* __restrict__ lead_sr,
                                                  float* __restrict__ filt) {
  const int bc = blockIdx.x;
  const int b = bc >> 7, c = bc & 127;
  const int tid = threadIdx.x;
  __shared__ float caL[C_], rL[C_];
  __shared__ int tL[C_];
  __shared__ float xrowL[L_];
  __shared__ float cfL[K_], srL[K_], pL[S_], qL[S_ * K_], praw[S_];
  __shared__ int leadL[K_], ltL[K_];

  const float* xb = x + (size_t)b * L_ * C_ + c;
  for (int l = tid; l < L_; l += 256) xrowL[l] = xb[(size_t)l * C_];
  if (tid < C_) {
    const float r = r_arr[(size_t)bc * C_ + tid];
    rL[tid] = r; caL[tid] = fabsf(r);
    tL[tid] = t_arr[(size_t)bc * C_ + tid];
  }
  __syncthreads();

  if (tid == 0) {
    const float T = temperature[0];
    float lg[K_ + 1];
    lg[0] = 1.0f / T;
    for (int k = 0; k < K_; ++k) {       // stable top-k: strict > keeps smallest index on ties
      float bvv = -1.f; int bi = 0;
      for (int jj = 0; jj < C_; ++jj) { const float v = caL[jj]; if (v > bvv) { bvv = v; bi = jj; } }
      leadL[k] = bi; ltL[k] = tL[bi];
      const float rv = rL[bi];
      srL[k] = (rv > 0.f) ? 1.f : ((rv < 0.f) ? -1.f : 0.f);
      lg[k + 1] = bvv / T;
      caL[bi] = -2.f;
    }
    float m = lg[0];
    for (int k = 1; k <= K_; ++k) m = fmaxf(m, lg[k]);
    float sum = 0.f, e[K_ + 1];
    for (int k = 0; k <= K_; ++k) { e[k] = expf(lg[k] - m); sum += e[k]; }
    const float invs = 1.0f / sum;
    for (int k = 0; k < K_; ++k) cfL[k] = e[k + 1] * invs;
  }
  __syncthreads();

  // p logits: 8 groups of 32 lanes, one state each
  {
    const int gg = tid >> 5, lane = tid & 31;
    float acc = 0.f;
    const float* w = cls_w + (size_t)gg * L_;
    for (int l = lane; l < L_; l += 32) acc += xrowL[l] * w[l];
    for (int off = 16; off; off >>= 1) acc += __shfl_down(acc, off, 32);
    if (lane == 0) praw[gg] = acc + state_bias[gg] + basic_state[c * S_ + gg];
  }
  __syncthreads();
  if (tid == 0) {
    float m = praw[0];
    for (int s2 = 1; s2 < S_; ++s2) m = fmaxf(m, praw[s2]);
    float sum = 0.f;
    for (int s2 = 0; s2 < S_; ++s2) { const float e = expf(praw[s2] - m); pL[s2] = e; sum += e; }
    const float invs = 1.0f / sum;
    for (int s2 = 0; s2 < S_; ++s2) pL[s2] *= invs;
    for (int s2 = 0; s2 < S_; ++s2)
      for (int k = 0; k < K_; ++k) qL[s2 * K_ + k] = pL[s2] * cfL[k];
  }
  __syncthreads();

  for (int o = tid; o < OUT_; o += 256) {
    float acc = 0.f;
#pragma unroll
    for (int s2 = 0; s2 < S_; ++s2) {
      acc += pL[s2] * mhb[s2 * OUT_ + o];
#pragma unroll
      for (int k = 0; k < K_; ++k)
        acc += qL[s2 * K_ + k] * mhw[(size_t)s2 * (K_ * OUT_) + k * OUT_ + o];
    }
    filt[(size_t)bc * OUT_ + o] = acc;
  }
  if (tid < K_) {
    lead_id[bc * K_ + tid] = leadL[tid];
    lead_t[bc * K_ + tid] = ltL[tid];
    lead_sr[bc * K_ + tid] = srL[tid];
  }
}

// ---------------------------------------------------------------- K4: spectral mix + output
__global__ __launch_bounds__(256) void k4_final(const float* __restrict__ seq,
                                                const float* __restrict__ mu_g,
                                                const float* __restrict__ std_g,
                                                const int* __restrict__ lead_id,
                                                const int* __restrict__ lead_t,
                                                const float* __restrict__ lead_sr,
                                                const float* __restrict__ filt,
                                                const float* __restrict__ mwr,
                                                const float* __restrict__ mwi,
                                                const float* __restrict__ mbr,
                                                const float* __restrict__ mbi,
                                                float* __restrict__ out) {
  const int bc = blockIdx.x;
  const int b = bc >> 7, c = bc & 127;
  const int tid = threadIdx.x;
  __shared__ float cosT[96], sinT[96];
  __shared__ float ssL[K_][H_], ynL[H_], flL[OUT_];
  __shared__ float sfr[K_][F2_], sfi[K_][F2_], yfr[F2_], yfi[F2_];
  __shared__ float catr[3 * F2_], cati[3 * F2_], ofr[F2_], ofi[F2_];
  __shared__ int ldL[K_], ltL[K_];
  __shared__ float srL[K_];

  if (tid < 96) {
    const float ang = (float)tid * (float)(6.283185307179586 / 96.0);
    cosT[tid] = cosf(ang); sinT[tid] = sinf(ang);
    ynL[tid] = seq[(size_t)bc * SEQLEN + L_ + tid];
  }
  if (tid >= 96 && tid < 96 + K_) {
    const int k = tid - 96;
    ldL[k] = lead_id[bc * K_ + k];
    ltL[k] = lead_t[bc * K_ + k];
    srL[k] = lead_sr[bc * K_ + k];
  }
  for (int o = tid; o < OUT_; o += 256) flL[o] = filt[(size_t)bc * OUT_ + o];
  __syncthreads();

  for (int i = tid; i < K_ * H_; i += 256) {     // gather shifted leader windows
    const int k = i / H_, h = i - k * H_;
    ssL[k][h] = seq[((size_t)(b * C_ + ldL[k])) * SEQLEN + (L_ + h - ltL[k])] * srL[k];
  }
  __syncthreads();

  for (int u = tid; u < K_ * F2_ + F2_; u += 256) {    // 96-pt rfft (DFT) of ss rows and yn
    if (u < K_ * F2_) {
      const int k = u / F2_, f = u - k * F2_;
      float re = 0.f, im = 0.f; int m = 0;
      for (int h = 0; h < H_; ++h) {
        const float v = ssL[k][h];
        re = fmaf(v, cosT[m], re); im = fmaf(-v, sinT[m], im);
        m += f; if (m >= 96) m -= 96;
      }
      sfr[k][f] = re; sfi[k][f] = im;
    } else {
      const int f = u - K_ * F2_;
      float re = 0.f, im = 0.f; int m = 0;
      for (int h = 0; h < H_; ++h) {
        const float v = ynL[h];
        re = fmaf(v, cosT[m], re); im = fmaf(-v, sinT[m], im);
        m += f; if (m >= 96) m -= 96;
      }
      yfr[f] = re; yfi[f] = im;
    }
  }
  __syncthreads();

  if (tid < F2_) {
    const int f = tid;
    float s1r = 0.f, s1i = 0.f, s2r = 0.f, s2i = 0.f;
    const float yr = yfr[f], yi = yfi[f];
#pragma unroll
    for (int k = 0; k < K_; ++k) {
      const float fa = flL[k * F2_ + f], fb = flL[(K_ + k) * F2_ + f];
      const float ar = sfr[k][f] * fa, ai = sfi[k][f] * fa;
      s1r += ar; s1i += ai;
      s2r += (ar - yr) * fb; s2i += (ai - yi) * fb;
    }
    const float fc = flL[2 * K_ * F2_ + f];
    catr[f] = s1r;            cati[f] = s1i;
    catr[F2_ + f] = s2r;      cati[F2_ + f] = s2i;
    catr[2 * F2_ + f] = yr * fc; cati[2 * F2_ + f] = yi * fc;
  }
  __syncthreads();

  if (tid < F2_) {
    const int o = tid;
    float ar = mbr[o], ai = mbi[o];
    const float* wr = mwr + (size_t)o * (3 * F2_);
    const float* wi = mwi + (size_t)o * (3 * F2_);
    for (int f = 0; f < 3 * F2_; ++f) {
      const float cr = catr[f], ci = cati[f];
      const float wrr = wr[f], wii = wi[f];
      ar += cr * wrr - ci * wii;
      ai += cr * wii + ci * wrr;
    }
    ofr[o] = ar; ofi[o] = ai;
  }
  __syncthreads();

  if (tid < H_) {
    const int h = tid;
    float val = ofr[0] + ofr[48] * ((h & 1) ? -1.f : 1.f);
    int m = h;                                  // (f*h)%96 for f=1
    for (int f = 1; f < 48; ++f) {
      val += 2.f * (ofr[f] * cosT[m] - ofi[f] * sinT[m]);
      m += h; if (m >= 96) m -= 96;
    }
    val *= (1.0f / 96.0f);
    const float mu = mu_g[bc], stdv = std_g[bc];
    out[((size_t)b * H_ + h) * C_ + c] = (ynL[h] + val) * stdv + mu;
  }
}

// ---------------------------------------------------------------- launch
extern "C" void kernel_launch(void* const* d_in, const int* in_sizes, int n_in,
                              void* d_out, int out_size, void* d_ws, size_t ws_size,
                              hipStream_t stream) {
  const float* x    = (const float*)d_in[0];
  const float* yh   = (const float*)d_in[1];
  const float* temp = (const float*)d_in[2];
  const float* clsw = (const float*)d_in[3];
  const float* bst  = (const float*)d_in[4];
  const float* sbias= (const float*)d_in[5];
  const float* mhw  = (const float*)d_in[6];
  const float* mhb  = (const float*)d_in[7];
  const float* mwr  = (const float*)d_in[8];
  const float* mwi  = (const float*)d_in[9];
  const float* mbr  = (const float*)d_in[10];
  const float* mbi  = (const float*)d_in[11];
  float* out = (float*)d_out;

  float* ws = (float*)d_ws;
  float* seq    = ws;                                   // 2048*816
  float* mu_g   = seq + (size_t)2048 * SEQLEN;          // 2048
  float* std_g  = mu_g + 2048;                          // 2048
  float* r_arr  = std_g + 2048;                         // 262144
  float* filt   = r_arr + (size_t)2048 * C_;            // 2048*833
  int*   t_arr  = (int*)(filt + (size_t)2048 * OUT_);   // 262144
  int*   lead_i = t_arr + (size_t)2048 * C_;            // 16384
  int*   lead_t = lead_i + 2048 * K_;                   // 16384
  float* lead_s = (float*)(lead_t + 2048 * K_);         // 16384
  float2* wtab  = (float2*)(lead_s + 2048 * K_);        // 720 float2

  // Forward spectra alias the filt region (5.91 MB <= 6.82 MB):
  // k1f writes Rc -> k2 reads Rc -> k3 overwrites filt. Safe every replay.
  float2* Rc = (float2*)filt;

  hipLaunchKernelGGL(k0_tab, dim3(1), dim3(256), 0, stream, wtab);
  hipLaunchKernelGGL(k1_norm, dim3(B_ * C_), dim3(256), 0, stream, x, yh, seq, mu_g, std_g);
  hipLaunchKernelGGL(k1f_fwd, dim3(B_ * C_), dim3(256), 0, stream, seq, wtab, Rc);
  hipLaunchKernelGGL(k2_fft, dim3(B_ * 576), dim3(256), 0, stream, Rc, wtab, r_arr, t_arr);
  hipLaunchKernelGGL(k3_leaders, dim3(B_ * C_), dim3(256), 0, stream,
                     x, temp, clsw, bst, sbias, mhw, mhb, r_arr, t_arr,
                     lead_i, lead_t, lead_s, filt);
  hipLaunchKernelGGL(k4_final, dim3(B_ * C_), dim3(256), 0, stream,
                     seq, mu_g, std_g, lead_i, lead_t, lead_s, filt,
                     mwr, mwi, mbr, mbi, out);
}